// Round 5
// baseline (350.929 us; speedup 1.0000x reference)
//
#include <hip/hip_runtime.h>
#include <hip/hip_bf16.h>
#include <cmath>

#define NSP 119
#define UNITS 512
#define NFEAT 360
#define KP1 384          // NFEAT padded to multiple of 32

typedef __attribute__((ext_vector_type(8))) short short8;
typedef __attribute__((ext_vector_type(4))) float floatx4;

// compile-time symmetric-index helpers (fold under full unroll)
__device__ __host__ constexpr int s2c(int i, int j) {
    return (i > j) ? i*(i+1)/2 + j : j*(j+1)/2 + i;
}
__device__ __host__ constexpr int s3c(int x, int y, int z) {
    int A = x > y ? x : y; A = A > z ? A : z;
    int C = x < y ? x : y; C = C < z ? C : z;
    int B = x + y + z - A - C;
    return A*(A+1)*(A+2)/6 + B*(B+1)/2 + C;
}

struct BasisConsts {
    float f0k;      // -betta * log2(e)
    float kg;       // 2*betta*delta*log2(e)
    float scale;    // rad_norm / sqrt(7)
    float c[6];     // exp(-betta*delta*(1 + delta*(2b+1)))
};

// ---------- phase 0: fused prep: tiled W transposes + init counts/out/gcount ----------
// blocks 0..191   : W1 (360x512 -> 512x384 bf16), 12 k-tiles x 16 n-tiles
// blocks 192..447 : W2 (512x512 -> 512x512 bf16), 16 x 16
// blocks 448..    : counts=0, out=(Z>0)?0.1*b3:0, gcount=0
__global__ __launch_bounds__(256) void prep_kernel(
    const float* __restrict__ W1, const float* __restrict__ W2,
    __hip_bfloat16* __restrict__ W1t, __hip_bfloat16* __restrict__ W2t,
    int* __restrict__ counts, float* __restrict__ outbuf,
    const int* __restrict__ Z, const float* __restrict__ b3,
    int* __restrict__ gcount, int natoms)
{
    int b = blockIdx.x;
    if (b < 448) {
        __shared__ float tile[32][33];
        const float* W; __hip_bfloat16* Wt; int K, Kp, ik, in;
        if (b < 192) { W = W1; Wt = W1t; K = NFEAT; Kp = KP1; ik = b % 12; in = b / 12; }
        else { int b2 = b - 192; W = W2; Wt = W2t; K = UNITS; Kp = UNITS; ik = b2 & 15; in = b2 >> 4; }
        int tx = threadIdx.x & 31, ty = threadIdx.x >> 5;
        int n = in * 32 + tx;                      // N = 512 for both matrices
        #pragma unroll
        for (int pp = 0; pp < 4; ++pp) {
            int kk = ty + pp * 8;
            int k = ik * 32 + kk;
            tile[kk][tx] = (k < K) ? W[(size_t)k * UNITS + n] : 0.f;
        }
        __syncthreads();
        #pragma unroll
        for (int pp = 0; pp < 4; ++pp) {
            int nn = ty + pp * 8;
            Wt[(size_t)(in * 32 + nn) * Kp + ik * 32 + tx] = __float2bfloat16(tile[tx][nn]);
        }
    } else {
        int idx = (b - 448) * 256 + threadIdx.x;
        if (idx < natoms) {
            counts[idx] = 0;
            outbuf[idx] = (Z[idx] > 0) ? 0.1f * b3[0] : 0.f;
        }
        if (idx == 0) gcount[0] = 0;
    }
}

// ---------- phase 1a (single geometry+emb pass): compact valid-pair records ----------
// One pass computes dr2, validity, the 8-float record; wave-aggregated atomic
// assigns a compact slot; counts[i] histogrammed here too.
__global__ __launch_bounds__(256) void pair_compute_kernel(
    const float* __restrict__ R, const int* __restrict__ Z,
    const int* __restrict__ nbr, const float* __restrict__ offsets,
    const float* __restrict__ emb, int* __restrict__ counts,
    int* __restrict__ gcount, float* __restrict__ tmpRec,
    int* __restrict__ tmpI, int npairs, BasisConsts bc)
{
    int p = blockIdx.x * 256 + threadIdx.x;
    int lane = threadIdx.x & 63;
    bool inr = p < npairs;
    int i = 0, j = 0;
    float dx = 0.f, dy = 0.f, dz = 0.f;
    if (inr) {
        i = nbr[p];
        j = nbr[npairs + p];
        dx = R[3*j]   - R[3*i]   + offsets[3*p];
        dy = R[3*j+1] - R[3*i+1] + offsets[3*p+1];
        dz = R[3*j+2] - R[3*i+2] + offsets[3*p+2];
    }
    float dr2 = fmaf(dz, dz, fmaf(dy, dy, dx*dx));
    bool valid = inr && (dr2 < 36.0f);

    unsigned long long mask = __ballot(valid);
    if (mask == 0ull) return;
    int cnt = __popcll(mask);
    int prefix = __popcll(mask & ((1ull << lane) - 1ull));
    int leader = __ffsll((unsigned long long)mask) - 1;
    int base = 0;
    if (lane == leader) base = atomicAdd(gcount, cnt);
    base = __shfl(base, leader, 64);
    if (!valid) return;
    int pos = base + prefix;

    atomicAdd(&counts[i], 1);

    float dr  = sqrtf(dr2);
    float inv = 1.0f / (dr + 1e-5f);
    float d0  = dr - 0.5f;
    float basis[7];
    basis[0] = exp2f(bc.f0k * d0 * d0);
    float G  = exp2f(bc.kg * dr);
    float cur = basis[0];
    #pragma unroll
    for (int b = 0; b < 6; ++b) { cur *= G * bc.c[b]; basis[b+1] = cur; }
    float cut = 0.5f * (__cosf(dr * 0.52359877559829887f) + 1.0f);  // pi/R_MAX
    float s = bc.scale * cut;

    const float* e = emb + ((size_t)Z[j] * NSP + Z[i]) * 35;
    float ev[35];
    __builtin_memcpy(ev, e, 35 * sizeof(float));

    float rec[8];
    #pragma unroll
    for (int r = 0; r < 5; ++r) {
        float acc = 0.f;
        #pragma unroll
        for (int b = 0; b < 7; ++b) acc += ev[r*7+b] * basis[b];
        rec[r] = s * acc;
    }
    rec[5] = dx * inv; rec[6] = dy * inv; rec[7] = dz * inv;
    tmpI[pos] = i;
    float4* out = (float4*)(tmpRec + (size_t)pos * 8);
    out[0] = make_float4(rec[0], rec[1], rec[2], rec[3]);
    out[1] = make_float4(rec[4], rec[5], rec[6], rec[7]);
}

// ---------- phase 1b: exclusive scan, single block, 32 items/thread, int4 I/O ----------
__global__ __launch_bounds__(1024) void scan_kernel(
    const int* __restrict__ counts, int* __restrict__ offs,
    int* __restrict__ cursor, int n)
{
    int tid = threadIdx.x;
    int lane = tid & 63, wid = tid >> 6;
    int beg = tid * 32;
    int local[32];
    int s = 0;
    if (beg + 32 <= n) {
        int4 w[8];
        const int4* cp = (const int4*)(counts + beg);
        #pragma unroll
        for (int j = 0; j < 8; ++j) w[j] = cp[j];
        const int* wf = (const int*)w;
        #pragma unroll
        for (int k = 0; k < 32; ++k) { local[k] = s; s += wf[k]; }
    } else {
        #pragma unroll
        for (int k = 0; k < 32; ++k) {
            int idx = beg + k;
            int v = (idx < n) ? counts[idx] : 0;
            local[k] = s; s += v;
        }
    }
    int incl = s;
    #pragma unroll
    for (int off = 1; off < 64; off <<= 1) {
        int t = __shfl_up(incl, off, 64);
        if (lane >= off) incl += t;
    }
    __shared__ int wsum[16];
    if (lane == 63) wsum[wid] = incl;
    __syncthreads();
    if (tid < 16) {
        int v = wsum[tid];
        int inc2 = v;
        #pragma unroll
        for (int off = 1; off < 16; off <<= 1) {
            int t = __shfl_up(inc2, off, 64);
            if (tid >= off) inc2 += t;
        }
        wsum[tid] = inc2 - v;
    }
    __syncthreads();
    int base = wsum[wid] + (incl - s);
    if (beg + 32 <= n) {
        int4* op = (int4*)(offs + beg);
        int4* cp2 = (int4*)(cursor + beg);
        #pragma unroll
        for (int j = 0; j < 8; ++j) {
            int4 t;
            t.x = base + local[j*4];   t.y = base + local[j*4+1];
            t.z = base + local[j*4+2]; t.w = base + local[j*4+3];
            op[j] = t; cp2[j] = t;
        }
    } else {
        #pragma unroll
        for (int k = 0; k < 32; ++k) {
            int idx = beg + k;
            if (idx < n) { int v = base + local[k]; offs[idx] = v; cursor[idx] = v; }
        }
    }
}

// ---------- phase 1c: scatter compact indices into per-atom segments (no geometry) ----------
__global__ __launch_bounds__(256) void scatter_idx_kernel(
    const int* __restrict__ tmpI, const int* __restrict__ gcount,
    int* __restrict__ cursor, int* __restrict__ sorted)
{
    int t = blockIdx.x * 256 + threadIdx.x;
    if (t >= *gcount) return;
    int i = tmpI[t];
    int pos = atomicAdd(&cursor[i], 1);
    sorted[pos] = t;
}

// ---------- phase 2a: one wave per atom -> 100 compressed moments to global ----------
// Staged record (28 floats): [0..4]=rad, [5..24]=poly(1, dn, sym2[6], sym3[10]).
// Inner loop: acc += s[cr] * s[5+pk]  (4 LDS reads + 2 FMA per pair, conflict-free).
// momG blocked layout: momG[(a>>6)*6400 + e*64 + (a&63)], e = 0..99
//   e 0..4: M0 | 5..19: M1[r*3+x] | 20..49: M2[r*6+s2c] | 50..99: M3[r*10+s3c]
#define SREC 28
__global__ __launch_bounds__(256) void moment_kernel(
    const float* __restrict__ tmpRec, const int* __restrict__ sorted,
    const int* __restrict__ offs, const int* __restrict__ counts,
    float* __restrict__ momG, int natoms)
{
    int wv = threadIdx.x >> 6, lane = threadIdx.x & 63;
    int a = blockIdx.x * 4 + wv;
    __shared__ float stage[4][64][SREC];

    int start = 0, cnt = 0;
    if (a < natoms) { start = offs[a]; cnt = counts[a]; }   // pad atoms: zeros

    // lane -> (cr0, pk0) for moment element e = lane (0..63)
    int cr0, pk0;
    if (lane < 5)       { cr0 = lane;            pk0 = 0; }
    else if (lane < 20) { int c = lane - 5;      cr0 = c / 3;  pk0 = 1 + c % 3; }
    else if (lane < 50) { int c = lane - 20;     cr0 = c / 6;  pk0 = 4 + c % 6; }
    else                { int c = lane - 50;     cr0 = c / 10; pk0 = 10 + c % 10; }
    // lane -> (cr1, pk1) for element e = 64 + lane (lane < 36)
    int cr1 = 0, pk1 = 0;
    if (lane < 36) { int c = 14 + lane; cr1 = c / 10; pk1 = 10 + c % 10; }

    float acc0 = 0.f, acc1 = 0.f;
    for (int base = 0; base < cnt; base += 64) {
        int m = min(64, cnt - base);
        if (lane < m) {
            int t = sorted[start + base + lane];
            const float4* pd = (const float4*)(tmpRec + (size_t)t * 8);
            float4 u = pd[0], v = pd[1];
            float x = v.y, y = v.z, z = v.w;
            float s2_0 = x*x, s2_1 = y*x, s2_2 = y*y, s2_3 = z*x, s2_4 = z*y, s2_5 = z*z;
            float* st = stage[wv][lane];
            ((float4*)st)[0] = u;                                    // rad0..3
            ((float4*)st)[1] = make_float4(v.x, 1.0f, x, y);         // rad4, p0=1, p1, p2
            ((float4*)st)[2] = make_float4(z, s2_0, s2_1, s2_2);     // p3..p6
            ((float4*)st)[3] = make_float4(s2_3, s2_4, s2_5, s2_0*x);// p7..p9, p10=xxx
            ((float4*)st)[4] = make_float4(s2_0*y, s2_2*x, s2_2*y, s2_0*z); // p11..p14
            ((float4*)st)[5] = make_float4(s2_1*z, s2_2*z, s2_5*x, s2_5*y); // p15..p18
            ((float4*)st)[6] = make_float4(s2_5*z, 0.f, 0.f, 0.f);   // p19, pad
        }
        __builtin_amdgcn_wave_barrier();
        for (int q = 0; q < m; ++q) {
            const float* s = stage[wv][q];
            acc0 += s[cr0] * s[5 + pk0];
            acc1 += s[cr1] * s[5 + pk1];
        }
        __builtin_amdgcn_wave_barrier();
    }
    size_t base = (size_t)(a >> 6) * 6400 + (size_t)(a & 63);
    momG[base + (size_t)lane * 64] = acc0;
    if (lane < 36) momG[base + (size_t)(64 + lane) * 64] = acc1;
}

// ---------- phase 2b: lane = atom, wave = feature group; all indices constexpr ----------
#define LROW 390   // LDS row stride in bf16: 195 words, 195%32=3 -> conflict-free
__global__ __launch_bounds__(256) void feat_kernel(
    const float* __restrict__ momG, __hip_bfloat16* __restrict__ feats)
{
    constexpr int cT2I[15] = {0,1,1,2,2,2,3,3,3,3,4,4,4,4,4};
    constexpr int cT2J[15] = {0,0,1,0,1,2,0,1,2,3,0,1,2,3,4};
    constexpr int cT3A[35] = {0, 1,1,1, 2,2,2,2,2,2, 3,3,3,3,3,3,3,3,3,3, 4,4,4,4,4,4,4,4,4,4,4,4,4,4,4};
    constexpr int cT3B[35] = {0, 0,1,1, 0,1,1,2,2,2, 0,1,1,2,2,2,3,3,3,3, 0,1,1,2,2,2,3,3,3,3,4,4,4,4,4};
    constexpr int cT3C[35] = {0, 0,0,1, 0,0,1,0,1,2, 0,0,1,0,1,2,0,1,2,3, 0,0,1,0,1,2,0,1,2,3,0,1,2,3,4};
    constexpr float cW2[6]  = {1.f,2.f,1.f,2.f,2.f,1.f};
    constexpr float cW3[10] = {1.f,3.f,3.f,1.f,3.f,6.f,3.f,3.f,3.f,1.f};

    __shared__ __hip_bfloat16 ldsF[64][LROW];
    int wv = threadIdx.x >> 6, lane = threadIdx.x & 63;
    const float* mg = momG + (size_t)blockIdx.x * 6400 + lane;

    #define LDM(e) mg[(e) * 64]
    #define STF(f, v) ldsF[lane][(f)] = __float2bfloat16(v)

    if (wv == 0) {
        // c6 for p = 0..9  -> feats 160 + p*5 + t
        float m3[50], m2[30];
        #pragma unroll
        for (int e = 0; e < 50; ++e) m3[e] = LDM(50 + e);
        #pragma unroll
        for (int e = 0; e < 30; ++e) m2[e] = LDM(20 + e);
        #pragma unroll
        for (int p = 0; p < 10; ++p) {
            int r = cT2I[p], s = cT2J[p];
            float B2v[9];
            #pragma unroll
            for (int z = 0; z < 3; ++z)
                #pragma unroll
                for (int w = 0; w < 3; ++w) {
                    float acc = 0.f;
                    #pragma unroll
                    for (int x = 0; x < 3; ++x)
                        #pragma unroll
                        for (int y = 0; y < 3; ++y)
                            acc += m3[r*10 + s3c(x,y,z)] * m3[s*10 + s3c(x,y,w)];
                    B2v[z*3+w] = acc;
                }
            #pragma unroll
            for (int t = 0; t < 5; ++t) {
                float acc = 0.f;
                #pragma unroll
                for (int z = 0; z < 3; ++z)
                    #pragma unroll
                    for (int w = 0; w < 3; ++w)
                        acc += B2v[z*3+w] * m2[t*6 + s2c(z,w)];
                STF(160 + p*5 + t, acc);
            }
        }
    } else if (wv == 1) {
        // M0, c1, c2, c4, zero-pad
        float m0[5], m1[15], m2[30];
        #pragma unroll
        for (int e = 0; e < 5; ++e)  m0[e] = LDM(e);
        #pragma unroll
        for (int e = 0; e < 15; ++e) m1[e] = LDM(5 + e);
        #pragma unroll
        for (int e = 0; e < 30; ++e) m2[e] = LDM(20 + e);
        #pragma unroll
        for (int r = 0; r < 5; ++r) STF(r, m0[r]);
        #pragma unroll
        for (int p = 0; p < 15; ++p) {
            int r = cT2I[p], s = cT2J[p];
            float v1 = m1[r*3]*m1[s*3] + m1[r*3+1]*m1[s*3+1] + m1[r*3+2]*m1[s*3+2];
            STF(5 + p, v1);
            float v2 = 0.f;
            #pragma unroll
            for (int k = 0; k < 6; ++k) v2 += cW2[k] * m2[r*6+k] * m2[s*6+k];
            STF(20 + p, v2);
        }
        #pragma unroll
        for (int q = 0; q < 35; ++q) {
            int r = cT3A[q], s = cT3B[q], t = cT3C[q];
            float v = 0.f;
            #pragma unroll
            for (int x = 0; x < 3; ++x)
                #pragma unroll
                for (int y = 0; y < 3; ++y) {
                    float d = 0.f;
                    #pragma unroll
                    for (int z = 0; z < 3; ++z)
                        d += m2[s*6 + s2c(x,z)] * m2[t*6 + s2c(y,z)];
                    v += m2[r*6 + s2c(x,y)] * d;
                }
            STF(50 + q, v);
        }
        #pragma unroll
        for (int f = NFEAT; f < KP1; ++f) STF(f, 0.f);
    } else if (wv == 2) {
        // c6 for p = 10..14, plus all of c5
        float m1[15], m2[30], m3[50];
        #pragma unroll
        for (int e = 0; e < 15; ++e) m1[e] = LDM(5 + e);
        #pragma unroll
        for (int e = 0; e < 30; ++e) m2[e] = LDM(20 + e);
        #pragma unroll
        for (int e = 0; e < 50; ++e) m3[e] = LDM(50 + e);
        #pragma unroll
        for (int p = 10; p < 15; ++p) {
            int r = cT2I[p], s = cT2J[p];
            float B2v[9];
            #pragma unroll
            for (int z = 0; z < 3; ++z)
                #pragma unroll
                for (int w = 0; w < 3; ++w) {
                    float acc = 0.f;
                    #pragma unroll
                    for (int x = 0; x < 3; ++x)
                        #pragma unroll
                        for (int y = 0; y < 3; ++y)
                            acc += m3[r*10 + s3c(x,y,z)] * m3[s*10 + s3c(x,y,w)];
                    B2v[z*3+w] = acc;
                }
            #pragma unroll
            for (int t = 0; t < 5; ++t) {
                float acc = 0.f;
                #pragma unroll
                for (int z = 0; z < 3; ++z)
                    #pragma unroll
                    for (int w = 0; w < 3; ++w)
                        acc += B2v[z*3+w] * m2[t*6 + s2c(z,w)];
                STF(160 + p*5 + t, acc);
            }
        }
        #pragma unroll
        for (int p = 0; p < 15; ++p) {
            int r = cT2I[p], s = cT2J[p];
            float o[9];
            #pragma unroll
            for (int x = 0; x < 3; ++x)
                #pragma unroll
                for (int y = 0; y < 3; ++y) o[x*3+y] = m1[r*3+x] * m1[s*3+y];
            #pragma unroll
            for (int t = 0; t < 5; ++t) {
                float v = 0.f;
                #pragma unroll
                for (int x = 0; x < 3; ++x)
                    #pragma unroll
                    for (int y = 0; y < 3; ++y)
                        v += o[x*3+y] * m2[t*6 + s2c(x,y)];
                STF(85 + p*5 + t, v);
            }
        }
    } else {
        // c3, c7
        float m1[15], m2[30], m3[50];
        #pragma unroll
        for (int e = 0; e < 15; ++e) m1[e] = LDM(5 + e);
        #pragma unroll
        for (int e = 0; e < 30; ++e) m2[e] = LDM(20 + e);
        #pragma unroll
        for (int e = 0; e < 50; ++e) m3[e] = LDM(50 + e);
        #pragma unroll
        for (int p = 0; p < 15; ++p) {
            int r = cT2I[p], s = cT2J[p];
            float v = 0.f;
            #pragma unroll
            for (int k = 0; k < 10; ++k) v += cW3[k] * m3[r*10+k] * m3[s*10+k];
            STF(35 + p, v);
        }
        #pragma unroll
        for (int r = 0; r < 5; ++r)
            #pragma unroll
            for (int s = 0; s < 5; ++s) {
                float A3z[3];
                #pragma unroll
                for (int z = 0; z < 3; ++z) {
                    float v = 0.f;
                    #pragma unroll
                    for (int x = 0; x < 3; ++x)
                        #pragma unroll
                        for (int y = 0; y < 3; ++y)
                            v += m3[r*10 + s3c(x,y,z)] * m2[s*6 + s2c(x,y)];
                    A3z[z] = v;
                }
                #pragma unroll
                for (int t = 0; t < 5; ++t) {
                    float v = A3z[0]*m1[t*3] + A3z[1]*m1[t*3+1] + A3z[2]*m1[t*3+2];
                    STF(235 + r*25 + s*5 + t, v);
                }
            }
    }
    __syncthreads();

    // coalesced copy-out: wave wv handles rows wv*16 .. wv*16+15
    __hip_bfloat16* dst = feats + (size_t)blockIdx.x * 64 * KP1;
    #pragma unroll
    for (int rr = 0; rr < 16; ++rr) {
        int row = wv * 16 + rr;
        #pragma unroll
        for (int it = 0; it < 3; ++it) {
            uint32_t v = *(const uint32_t*)&ldsF[row][(it*64 + lane)*2];
            *(uint32_t*)&dst[(size_t)row * KP1 + (size_t)(it*64 + lane)*2] = v;
        }
    }
    #undef LDM
    #undef STF
}

// ---------- bf16 MFMA GEMM, 128x128 tile, BK=32, reg-staged double-buffer ----------
// 1D grid with XCD-grouped swizzle: mt = (bid>>5)*8 + (bid&7), nt = (bid>>3)&3.
__global__ __launch_bounds__(256) void gemm_mfma_swish(
    const __hip_bfloat16* __restrict__ A, const __hip_bfloat16* __restrict__ Bt,
    const float* __restrict__ bias, __hip_bfloat16* __restrict__ C,
    const float* __restrict__ w3, float* __restrict__ outacc,
    const int* __restrict__ Zmask,
    int Kp, int M, int Mtiles, float alpha, float a3, int fuse)
{
    __shared__ float4 As[2][512];   // 128 rows x 4 chunks (32 bf16/row)
    __shared__ float4 Bs[2][512];   // 128 rows x 4 chunks
    int tid = threadIdx.x;
    int wave = tid >> 6, lane = tid & 63;
    int quad = lane >> 4, l16 = lane & 15;
    int wm = wave >> 1, wn = wave & 1;   // 2x2 waves: 64-row x 64-col each
    int bid = blockIdx.x;
    int mt = (bid >> 5) * 8 + (bid & 7);
    int nt = (bid >> 3) & 3;
    if (mt >= Mtiles) return;
    int rowBase = mt * 128;
    int colBase = nt * 128;

    floatx4 acc[4][4] = {};

    int rA0 = tid >> 2, cA = tid & 3;   // rows 0..63
    int rA1 = rA0 + 64;                 // rows 64..127
    int pA0 = rA0 * 4 + (cA ^ ((rA0 >> 1) & 3));
    int pA1 = rA1 * 4 + (cA ^ ((rA1 >> 1) & 3));

    const char* pa0 = (const char*)(A  + (size_t)(rowBase + rA0) * Kp + cA * 8);
    const char* pa1 = (const char*)(A  + (size_t)(rowBase + rA1) * Kp + cA * 8);
    const char* pb0 = (const char*)(Bt + (size_t)(colBase + rA0) * Kp + cA * 8);
    const char* pb1 = (const char*)(Bt + (size_t)(colBase + rA1) * Kp + cA * 8);

    int posA[4], posB[4];
    #pragma unroll
    for (int t = 0; t < 4; ++t) {
        int rr = wm * 64 + t * 16 + l16;
        posA[t] = rr * 4 + (quad ^ ((rr >> 1) & 3));
    }
    #pragma unroll
    for (int u = 0; u < 4; ++u) {
        int cc = wn * 64 + u * 16 + l16;
        posB[u] = cc * 4 + (quad ^ ((cc >> 1) & 3));
    }

    int nK = Kp >> 5;
    float4 ra0 = *(const float4*)pa0;
    float4 ra1 = *(const float4*)pa1;
    float4 rb0 = *(const float4*)pb0;
    float4 rb1 = *(const float4*)pb1;

    for (int kt = 0; kt < nK; ++kt) {
        int buf = kt & 1;
        As[buf][pA0] = ra0;
        As[buf][pA1] = ra1;
        Bs[buf][pA0] = rb0;
        Bs[buf][pA1] = rb1;
        __syncthreads();
        if (kt + 1 < nK) {
            int off = (kt + 1) << 6;   // 32 bf16 = 64 bytes
            ra0 = *(const float4*)(pa0 + off);
            ra1 = *(const float4*)(pa1 + off);
            rb0 = *(const float4*)(pb0 + off);
            rb1 = *(const float4*)(pb1 + off);
        }
        short8 af[4], bf[4];
        #pragma unroll
        for (int t = 0; t < 4; ++t) af[t] = *(const short8*)(As[buf] + posA[t]);
        #pragma unroll
        for (int u = 0; u < 4; ++u) bf[u] = *(const short8*)(Bs[buf] + posB[u]);
        #pragma unroll
        for (int t = 0; t < 4; ++t)
            #pragma unroll
            for (int u = 0; u < 4; ++u)
                acc[t][u] = __builtin_amdgcn_mfma_f32_16x16x32_bf16(
                    af[t], bf[u], acc[t][u], 0, 0, 0);
        // no trailing barrier: next iter writes the other LDS buffer
    }

    if (!fuse) {
        #pragma unroll
        for (int u = 0; u < 4; ++u) {
            int col = colBase + wn * 64 + u * 16 + l16;
            float bc = 0.1f * bias[col];
            #pragma unroll
            for (int t = 0; t < 4; ++t) {
                int row0 = rowBase + wm * 64 + t * 16 + quad * 4;
                #pragma unroll
                for (int r = 0; r < 4; ++r) {
                    float x = alpha * acc[t][u][r] + bc;
                    float v = x / (1.f + expf(-x));
                    C[(size_t)(row0 + r) * UNITS + col] = __float2bfloat16(v);
                }
            }
        }
    } else {
        float rowsum[4][4] = {};
        #pragma unroll
        for (int u = 0; u < 4; ++u) {
            int col = colBase + wn * 64 + u * 16 + l16;
            float bc = 0.1f * bias[col];
            float w3c = w3[col] * a3;
            #pragma unroll
            for (int t = 0; t < 4; ++t)
                #pragma unroll
                for (int r = 0; r < 4; ++r) {
                    float x = alpha * acc[t][u][r] + bc;
                    float v = x / (1.f + expf(-x));
                    rowsum[t][r] += v * w3c;
                }
        }
        #pragma unroll
        for (int t = 0; t < 4; ++t)
            #pragma unroll
            for (int r = 0; r < 4; ++r) {
                float s = rowsum[t][r];
                s += __shfl_xor(s, 1, 64);
                s += __shfl_xor(s, 2, 64);
                s += __shfl_xor(s, 4, 64);
                s += __shfl_xor(s, 8, 64);
                rowsum[t][r] = s;
            }
        if (l16 == 0) {
            #pragma unroll
            for (int t = 0; t < 4; ++t) {
                int row0 = rowBase + wm * 64 + t * 16 + quad * 4;
                #pragma unroll
                for (int r = 0; r < 4; ++r) {
                    int row = row0 + r;
                    if (row < M && Zmask[row] > 0)
                        atomicAdd(&outacc[row], rowsum[t][r]);
                }
            }
        }
    }
}

static inline size_t align_up(size_t x, size_t a) { return (x + a - 1) & ~(a - 1); }

extern "C" void kernel_launch(void* const* d_in, const int* in_sizes, int n_in,
                              void* d_out, int out_size, void* d_ws, size_t ws_size,
                              hipStream_t stream)
{
    const float* R       = (const float*)d_in[0];
    const int*   Z       = (const int*)  d_in[1];
    const int*   nbr     = (const int*)  d_in[2];
    const float* offsets = (const float*)d_in[4];
    const float* emb     = (const float*)d_in[5];
    const float* W1      = (const float*)d_in[6];
    const float* b1      = (const float*)d_in[7];
    const float* W2      = (const float*)d_in[8];
    const float* b2      = (const float*)d_in[9];
    const float* W3      = (const float*)d_in[10];
    const float* b3      = (const float*)d_in[11];

    int natoms = in_sizes[0] / 3;
    int npairs = in_sizes[2] / 2;
    int Mpad = ((natoms + 127) / 128) * 128;
    int Mtiles = Mpad / 128;

    char* ws = (char*)d_ws;
    size_t off = 0;
    int* counts = (int*)(ws + off); off = align_up(off + natoms*4, 256);
    int* offs   = (int*)(ws + off); off = align_up(off + natoms*4, 256);
    int* cursor = (int*)(ws + off); off = align_up(off + natoms*4, 256);
    int* gcount = (int*)(ws + off); off = align_up(off + 4, 256);
    int* tmpI   = (int*)(ws + off); off = align_up(off + (size_t)npairs*4, 256);
    int* sorted = (int*)(ws + off); off = align_up(off + (size_t)npairs*4, 256);
    float* tmpRec = (float*)(ws + off); off = align_up(off + (size_t)npairs*8*4, 256);
    float* momG = (float*)(ws + off); off = align_up(off + (size_t)Mpad*100*4, 256);
    __hip_bfloat16* W1t   = (__hip_bfloat16*)(ws + off); off = align_up(off + (size_t)UNITS*KP1*2, 256);
    __hip_bfloat16* W2t   = (__hip_bfloat16*)(ws + off); off = align_up(off + (size_t)UNITS*UNITS*2, 256);
    __hip_bfloat16* feats = (__hip_bfloat16*)(ws + off); off = align_up(off + (size_t)Mpad*KP1*2, 256);
    __hip_bfloat16* h1    = (__hip_bfloat16*)(ws + off); off = align_up(off + (size_t)Mpad*UNITS*2, 256);

    // host-side double-precision basis constants (exact vs numpy reference)
    BasisConsts bc;
    {
        const double betta = 49.0 / 36.0;
        const double delta = 5.5 / 6.0;
        const double log2e = 1.4426950408889634073599246810;
        bc.f0k = (float)(-betta * log2e);
        bc.kg  = (float)(2.0 * betta * delta * log2e);
        for (int b = 0; b < 6; ++b)
            bc.c[b] = (float)exp(-betta * delta * (1.0 + delta * (2*b + 1)));
        bc.scale = (float)(pow(2.0 * betta / M_PI, 0.75) / sqrt(7.0));
    }

    int prepBlocks = 448 + (natoms + 255) / 256;
    prep_kernel<<<dim3(prepBlocks), 256, 0, stream>>>(
        W1, W2, W1t, W2t, counts, (float*)d_out, Z, b3, gcount, natoms);

    int pgrid = (npairs + 255) / 256;
    pair_compute_kernel<<<dim3(pgrid), 256, 0, stream>>>(
        R, Z, nbr, offsets, emb, counts, gcount, tmpRec, tmpI, npairs, bc);
    scan_kernel<<<dim3(1), 1024, 0, stream>>>(counts, offs, cursor, natoms);
    scatter_idx_kernel<<<dim3(pgrid), 256, 0, stream>>>(tmpI, gcount, cursor, sorted);

    moment_kernel<<<dim3(Mpad / 4), 256, 0, stream>>>(
        tmpRec, sorted, offs, counts, momG, natoms);
    feat_kernel<<<dim3(Mpad / 64), 256, 0, stream>>>(momG, feats);

    float a1 = 1.0f / sqrtf((float)NFEAT);
    float a2 = 1.0f / sqrtf((float)UNITS);
    int gemmGrid = ((Mtiles + 7) / 8) * 8 * 4;
    gemm_mfma_swish<<<dim3(gemmGrid), 256, 0, stream>>>(
        feats, W1t, b1, h1, nullptr, nullptr, nullptr, KP1, natoms, Mtiles, a1, 0.f, 0);
    gemm_mfma_swish<<<dim3(gemmGrid), 256, 0, stream>>>(
        h1, W2t, b2, nullptr, W3, (float*)d_out, Z, UNITS, natoms, Mtiles, a2, a2, 1);
}

// Round 6
// 201.071 us; speedup vs baseline: 1.7453x; 1.7453x over previous
//
#include <hip/hip_runtime.h>
#include <hip/hip_bf16.h>
#include <cmath>

#define NSP 119
#define UNITS 512
#define NFEAT 360
#define KP1 384          // NFEAT padded to multiple of 32
#define CAP 128          // per-atom pair-segment capacity (mean ~21, >13 sigma)

typedef __attribute__((ext_vector_type(8))) short short8;
typedef __attribute__((ext_vector_type(4))) float floatx4;

// compile-time symmetric-index helpers (fold under full unroll)
__device__ __host__ constexpr int s2c(int i, int j) {
    return (i > j) ? i*(i+1)/2 + j : j*(j+1)/2 + i;
}
__device__ __host__ constexpr int s3c(int x, int y, int z) {
    int A = x > y ? x : y; A = A > z ? A : z;
    int C = x < y ? x : y; C = C < z ? C : z;
    int B = x + y + z - A - C;
    return A*(A+1)*(A+2)/6 + B*(B+1)/2 + C;
}

struct BasisConsts {
    float f0k;      // -betta * log2(e)
    float kg;       // 2*betta*delta*log2(e)
    float scale;    // rad_norm / sqrt(7)
    float c[6];     // exp(-betta*delta*(1 + delta*(2b+1)))
};

// ---------- phase 0: fused prep: tiled W transposes + init counts/out ----------
// blocks 0..191   : W1 (360x512 -> 512x384 bf16), 12 k-tiles x 16 n-tiles
// blocks 192..447 : W2 (512x512 -> 512x512 bf16), 16 x 16
// blocks 448..    : counts=0, out=(Z>0)?0.1*b3:0
__global__ __launch_bounds__(256) void prep_kernel(
    const float* __restrict__ W1, const float* __restrict__ W2,
    __hip_bfloat16* __restrict__ W1t, __hip_bfloat16* __restrict__ W2t,
    int* __restrict__ counts, float* __restrict__ outbuf,
    const int* __restrict__ Z, const float* __restrict__ b3, int natoms)
{
    int b = blockIdx.x;
    if (b < 448) {
        __shared__ float tile[32][33];
        const float* W; __hip_bfloat16* Wt; int K, Kp, ik, in;
        if (b < 192) { W = W1; Wt = W1t; K = NFEAT; Kp = KP1; ik = b % 12; in = b / 12; }
        else { int b2 = b - 192; W = W2; Wt = W2t; K = UNITS; Kp = UNITS; ik = b2 & 15; in = b2 >> 4; }
        int tx = threadIdx.x & 31, ty = threadIdx.x >> 5;
        int n = in * 32 + tx;                      // N = 512 for both matrices
        #pragma unroll
        for (int pp = 0; pp < 4; ++pp) {
            int kk = ty + pp * 8;
            int k = ik * 32 + kk;
            tile[kk][tx] = (k < K) ? W[(size_t)k * UNITS + n] : 0.f;
        }
        __syncthreads();
        #pragma unroll
        for (int pp = 0; pp < 4; ++pp) {
            int nn = ty + pp * 8;
            Wt[(size_t)(in * 32 + nn) * Kp + ik * 32 + tx] = __float2bfloat16(tile[tx][nn]);
        }
    } else {
        int idx = (b - 448) * 256 + threadIdx.x;
        if (idx < natoms) {
            counts[idx] = 0;
            outbuf[idx] = (Z[idx] > 0) ? 0.1f * b3[0] : 0.f;
        }
    }
}

// ---------- phase 1 (single pass): geometry + basis + emb -> per-atom segment ----------
// Slot via per-atom atomic (20k distinct counters -> no contention, no ordering
// dependency). Record written at fixed-stride segment tmpRec[(i*CAP+pos)*8].
__global__ __launch_bounds__(256) void pair_compute_kernel(
    const float* __restrict__ R, const int* __restrict__ Z,
    const int* __restrict__ nbr, const float* __restrict__ offsets,
    const float* __restrict__ emb, int* __restrict__ counts,
    float* __restrict__ tmpRec, int npairs, BasisConsts bc)
{
    int p = blockIdx.x * 256 + threadIdx.x;
    if (p >= npairs) return;
    int i = nbr[p];
    int j = nbr[npairs + p];
    float dx = R[3*j]   - R[3*i]   + offsets[3*p];
    float dy = R[3*j+1] - R[3*i+1] + offsets[3*p+1];
    float dz = R[3*j+2] - R[3*i+2] + offsets[3*p+2];
    float dr2 = fmaf(dz, dz, fmaf(dy, dy, dx*dx));
    if (dr2 >= 36.0f) return;
    int pos = atomicAdd(&counts[i], 1);
    if (pos >= CAP) return;   // statistically impossible; memory-safety guard

    float dr  = sqrtf(dr2);
    float inv = 1.0f / (dr + 1e-5f);
    float d0  = dr - 0.5f;
    float basis[7];
    basis[0] = exp2f(bc.f0k * d0 * d0);
    float G  = exp2f(bc.kg * dr);
    float cur = basis[0];
    #pragma unroll
    for (int b = 0; b < 6; ++b) { cur *= G * bc.c[b]; basis[b+1] = cur; }
    float cut = 0.5f * (__cosf(dr * 0.52359877559829887f) + 1.0f);  // pi/R_MAX
    float s = bc.scale * cut;

    const float* e = emb + ((size_t)Z[j] * NSP + Z[i]) * 35;
    float ev[35];
    __builtin_memcpy(ev, e, 35 * sizeof(float));

    float rec[8];
    #pragma unroll
    for (int r = 0; r < 5; ++r) {
        float acc = 0.f;
        #pragma unroll
        for (int b = 0; b < 7; ++b) acc += ev[r*7+b] * basis[b];
        rec[r] = s * acc;
    }
    rec[5] = dx * inv; rec[6] = dy * inv; rec[7] = dz * inv;
    float4* out = (float4*)(tmpRec + ((size_t)i * CAP + pos) * 8);
    out[0] = make_float4(rec[0], rec[1], rec[2], rec[3]);
    out[1] = make_float4(rec[4], rec[5], rec[6], rec[7]);
}

// ---------- phase 2a: one wave per atom -> 100 compressed moments to global ----------
// Staged record (28 floats): [0..4]=rad, [5..24]=poly(1, dn, sym2[6], sym3[10]).
// Inner loop: acc += s[cr] * s[5+pk]  (4 LDS reads + 2 FMA per pair).
// Segment reads are contiguous: 64 lanes x 32B = 2KB per iteration.
// momG blocked layout: momG[(a>>6)*6400 + e*64 + (a&63)], e = 0..99
//   e 0..4: M0 | 5..19: M1[r*3+x] | 20..49: M2[r*6+s2c] | 50..99: M3[r*10+s3c]
#define SREC 28
__global__ __launch_bounds__(256) void moment_kernel(
    const float* __restrict__ tmpRec, const int* __restrict__ counts,
    float* __restrict__ momG, int natoms)
{
    int wv = threadIdx.x >> 6, lane = threadIdx.x & 63;
    int a = blockIdx.x * 4 + wv;
    __shared__ float stage[4][64][SREC];

    int cnt = 0;
    if (a < natoms) cnt = min(counts[a], CAP);   // pad atoms: zeros

    // lane -> (cr0, pk0) for moment element e = lane (0..63)
    int cr0, pk0;
    if (lane < 5)       { cr0 = lane;            pk0 = 0; }
    else if (lane < 20) { int c = lane - 5;      cr0 = c / 3;  pk0 = 1 + c % 3; }
    else if (lane < 50) { int c = lane - 20;     cr0 = c / 6;  pk0 = 4 + c % 6; }
    else                { int c = lane - 50;     cr0 = c / 10; pk0 = 10 + c % 10; }
    // lane -> (cr1, pk1) for element e = 64 + lane (lane < 36)
    int cr1 = 0, pk1 = 0;
    if (lane < 36) { int c = 14 + lane; cr1 = c / 10; pk1 = 10 + c % 10; }

    float acc0 = 0.f, acc1 = 0.f;
    for (int base = 0; base < cnt; base += 64) {
        int m = min(64, cnt - base);
        if (lane < m) {
            const float4* pd = (const float4*)(tmpRec + ((size_t)a * CAP + base + lane) * 8);
            float4 u = pd[0], v = pd[1];
            float x = v.y, y = v.z, z = v.w;
            float s2_0 = x*x, s2_1 = y*x, s2_2 = y*y, s2_3 = z*x, s2_4 = z*y, s2_5 = z*z;
            float* st = stage[wv][lane];
            ((float4*)st)[0] = u;                                    // rad0..3
            ((float4*)st)[1] = make_float4(v.x, 1.0f, x, y);         // rad4, p0=1, p1, p2
            ((float4*)st)[2] = make_float4(z, s2_0, s2_1, s2_2);     // p3..p6
            ((float4*)st)[3] = make_float4(s2_3, s2_4, s2_5, s2_0*x);// p7..p9, p10=xxx
            ((float4*)st)[4] = make_float4(s2_0*y, s2_2*x, s2_2*y, s2_0*z); // p11..p14
            ((float4*)st)[5] = make_float4(s2_1*z, s2_2*z, s2_5*x, s2_5*y); // p15..p18
            ((float4*)st)[6] = make_float4(s2_5*z, 0.f, 0.f, 0.f);   // p19, pad
        }
        __builtin_amdgcn_wave_barrier();
        for (int q = 0; q < m; ++q) {
            const float* s = stage[wv][q];
            acc0 += s[cr0] * s[5 + pk0];
            acc1 += s[cr1] * s[5 + pk1];
        }
        __builtin_amdgcn_wave_barrier();
    }
    size_t base = (size_t)(a >> 6) * 6400 + (size_t)(a & 63);
    momG[base + (size_t)lane * 64] = acc0;
    if (lane < 36) momG[base + (size_t)(64 + lane) * 64] = acc1;
}

// ---------- phase 2b: lane = atom, wave = feature group; all indices constexpr ----------
#define LROW 390   // LDS row stride in bf16: 195 words, 195%32=3 -> conflict-free
__global__ __launch_bounds__(256) void feat_kernel(
    const float* __restrict__ momG, __hip_bfloat16* __restrict__ feats)
{
    constexpr int cT2I[15] = {0,1,1,2,2,2,3,3,3,3,4,4,4,4,4};
    constexpr int cT2J[15] = {0,0,1,0,1,2,0,1,2,3,0,1,2,3,4};
    constexpr int cT3A[35] = {0, 1,1,1, 2,2,2,2,2,2, 3,3,3,3,3,3,3,3,3,3, 4,4,4,4,4,4,4,4,4,4,4,4,4,4,4};
    constexpr int cT3B[35] = {0, 0,1,1, 0,1,1,2,2,2, 0,1,1,2,2,2,3,3,3,3, 0,1,1,2,2,2,3,3,3,3,4,4,4,4,4};
    constexpr int cT3C[35] = {0, 0,0,1, 0,0,1,0,1,2, 0,0,1,0,1,2,0,1,2,3, 0,0,1,0,1,2,0,1,2,3,0,1,2,3,4};
    constexpr float cW2[6]  = {1.f,2.f,1.f,2.f,2.f,1.f};
    constexpr float cW3[10] = {1.f,3.f,3.f,1.f,3.f,6.f,3.f,3.f,3.f,1.f};

    __shared__ __hip_bfloat16 ldsF[64][LROW];
    int wv = threadIdx.x >> 6, lane = threadIdx.x & 63;
    const float* mg = momG + (size_t)blockIdx.x * 6400 + lane;

    #define LDM(e) mg[(e) * 64]
    #define STF(f, v) ldsF[lane][(f)] = __float2bfloat16(v)

    if (wv == 0) {
        // c6 for p = 0..9  -> feats 160 + p*5 + t
        float m3[50], m2[30];
        #pragma unroll
        for (int e = 0; e < 50; ++e) m3[e] = LDM(50 + e);
        #pragma unroll
        for (int e = 0; e < 30; ++e) m2[e] = LDM(20 + e);
        #pragma unroll
        for (int p = 0; p < 10; ++p) {
            int r = cT2I[p], s = cT2J[p];
            float B2v[9];
            #pragma unroll
            for (int z = 0; z < 3; ++z)
                #pragma unroll
                for (int w = 0; w < 3; ++w) {
                    float acc = 0.f;
                    #pragma unroll
                    for (int x = 0; x < 3; ++x)
                        #pragma unroll
                        for (int y = 0; y < 3; ++y)
                            acc += m3[r*10 + s3c(x,y,z)] * m3[s*10 + s3c(x,y,w)];
                    B2v[z*3+w] = acc;
                }
            #pragma unroll
            for (int t = 0; t < 5; ++t) {
                float acc = 0.f;
                #pragma unroll
                for (int z = 0; z < 3; ++z)
                    #pragma unroll
                    for (int w = 0; w < 3; ++w)
                        acc += B2v[z*3+w] * m2[t*6 + s2c(z,w)];
                STF(160 + p*5 + t, acc);
            }
        }
    } else if (wv == 1) {
        // M0, c1, c2, c4, zero-pad
        float m0[5], m1[15], m2[30];
        #pragma unroll
        for (int e = 0; e < 5; ++e)  m0[e] = LDM(e);
        #pragma unroll
        for (int e = 0; e < 15; ++e) m1[e] = LDM(5 + e);
        #pragma unroll
        for (int e = 0; e < 30; ++e) m2[e] = LDM(20 + e);
        #pragma unroll
        for (int r = 0; r < 5; ++r) STF(r, m0[r]);
        #pragma unroll
        for (int p = 0; p < 15; ++p) {
            int r = cT2I[p], s = cT2J[p];
            float v1 = m1[r*3]*m1[s*3] + m1[r*3+1]*m1[s*3+1] + m1[r*3+2]*m1[s*3+2];
            STF(5 + p, v1);
            float v2 = 0.f;
            #pragma unroll
            for (int k = 0; k < 6; ++k) v2 += cW2[k] * m2[r*6+k] * m2[s*6+k];
            STF(20 + p, v2);
        }
        #pragma unroll
        for (int q = 0; q < 35; ++q) {
            int r = cT3A[q], s = cT3B[q], t = cT3C[q];
            float v = 0.f;
            #pragma unroll
            for (int x = 0; x < 3; ++x)
                #pragma unroll
                for (int y = 0; y < 3; ++y) {
                    float d = 0.f;
                    #pragma unroll
                    for (int z = 0; z < 3; ++z)
                        d += m2[s*6 + s2c(x,z)] * m2[t*6 + s2c(y,z)];
                    v += m2[r*6 + s2c(x,y)] * d;
                }
            STF(50 + q, v);
        }
        #pragma unroll
        for (int f = NFEAT; f < KP1; ++f) STF(f, 0.f);
    } else if (wv == 2) {
        // c6 for p = 10..14, plus all of c5
        float m1[15], m2[30], m3[50];
        #pragma unroll
        for (int e = 0; e < 15; ++e) m1[e] = LDM(5 + e);
        #pragma unroll
        for (int e = 0; e < 30; ++e) m2[e] = LDM(20 + e);
        #pragma unroll
        for (int e = 0; e < 50; ++e) m3[e] = LDM(50 + e);
        #pragma unroll
        for (int p = 10; p < 15; ++p) {
            int r = cT2I[p], s = cT2J[p];
            float B2v[9];
            #pragma unroll
            for (int z = 0; z < 3; ++z)
                #pragma unroll
                for (int w = 0; w < 3; ++w) {
                    float acc = 0.f;
                    #pragma unroll
                    for (int x = 0; x < 3; ++x)
                        #pragma unroll
                        for (int y = 0; y < 3; ++y)
                            acc += m3[r*10 + s3c(x,y,z)] * m3[s*10 + s3c(x,y,w)];
                    B2v[z*3+w] = acc;
                }
            #pragma unroll
            for (int t = 0; t < 5; ++t) {
                float acc = 0.f;
                #pragma unroll
                for (int z = 0; z < 3; ++z)
                    #pragma unroll
                    for (int w = 0; w < 3; ++w)
                        acc += B2v[z*3+w] * m2[t*6 + s2c(z,w)];
                STF(160 + p*5 + t, acc);
            }
        }
        #pragma unroll
        for (int p = 0; p < 15; ++p) {
            int r = cT2I[p], s = cT2J[p];
            float o[9];
            #pragma unroll
            for (int x = 0; x < 3; ++x)
                #pragma unroll
                for (int y = 0; y < 3; ++y) o[x*3+y] = m1[r*3+x] * m1[s*3+y];
            #pragma unroll
            for (int t = 0; t < 5; ++t) {
                float v = 0.f;
                #pragma unroll
                for (int x = 0; x < 3; ++x)
                    #pragma unroll
                    for (int y = 0; y < 3; ++y)
                        v += o[x*3+y] * m2[t*6 + s2c(x,y)];
                STF(85 + p*5 + t, v);
            }
        }
    } else {
        // c3, c7
        float m1[15], m2[30], m3[50];
        #pragma unroll
        for (int e = 0; e < 15; ++e) m1[e] = LDM(5 + e);
        #pragma unroll
        for (int e = 0; e < 30; ++e) m2[e] = LDM(20 + e);
        #pragma unroll
        for (int e = 0; e < 50; ++e) m3[e] = LDM(50 + e);
        #pragma unroll
        for (int p = 0; p < 15; ++p) {
            int r = cT2I[p], s = cT2J[p];
            float v = 0.f;
            #pragma unroll
            for (int k = 0; k < 10; ++k) v += cW3[k] * m3[r*10+k] * m3[s*10+k];
            STF(35 + p, v);
        }
        #pragma unroll
        for (int r = 0; r < 5; ++r)
            #pragma unroll
            for (int s = 0; s < 5; ++s) {
                float A3z[3];
                #pragma unroll
                for (int z = 0; z < 3; ++z) {
                    float v = 0.f;
                    #pragma unroll
                    for (int x = 0; x < 3; ++x)
                        #pragma unroll
                        for (int y = 0; y < 3; ++y)
                            v += m3[r*10 + s3c(x,y,z)] * m2[s*6 + s2c(x,y)];
                    A3z[z] = v;
                }
                #pragma unroll
                for (int t = 0; t < 5; ++t) {
                    float v = A3z[0]*m1[t*3] + A3z[1]*m1[t*3+1] + A3z[2]*m1[t*3+2];
                    STF(235 + r*25 + s*5 + t, v);
                }
            }
    }
    __syncthreads();

    // coalesced copy-out: wave wv handles rows wv*16 .. wv*16+15
    __hip_bfloat16* dst = feats + (size_t)blockIdx.x * 64 * KP1;
    #pragma unroll
    for (int rr = 0; rr < 16; ++rr) {
        int row = wv * 16 + rr;
        #pragma unroll
        for (int it = 0; it < 3; ++it) {
            uint32_t v = *(const uint32_t*)&ldsF[row][(it*64 + lane)*2];
            *(uint32_t*)&dst[(size_t)row * KP1 + (size_t)(it*64 + lane)*2] = v;
        }
    }
    #undef LDM
    #undef STF
}

// ---------- bf16 MFMA GEMM, 128x128 tile, BK=32, reg-staged double-buffer ----------
// 1D grid with XCD-grouped swizzle: mt = (bid>>5)*8 + (bid&7), nt = (bid>>3)&3.
__global__ __launch_bounds__(256) void gemm_mfma_swish(
    const __hip_bfloat16* __restrict__ A, const __hip_bfloat16* __restrict__ Bt,
    const float* __restrict__ bias, __hip_bfloat16* __restrict__ C,
    const float* __restrict__ w3, float* __restrict__ outacc,
    const int* __restrict__ Zmask,
    int Kp, int M, int Mtiles, float alpha, float a3, int fuse)
{
    __shared__ float4 As[2][512];   // 128 rows x 4 chunks (32 bf16/row)
    __shared__ float4 Bs[2][512];   // 128 rows x 4 chunks
    int tid = threadIdx.x;
    int wave = tid >> 6, lane = tid & 63;
    int quad = lane >> 4, l16 = lane & 15;
    int wm = wave >> 1, wn = wave & 1;   // 2x2 waves: 64-row x 64-col each
    int bid = blockIdx.x;
    int mt = (bid >> 5) * 8 + (bid & 7);
    int nt = (bid >> 3) & 3;
    if (mt >= Mtiles) return;
    int rowBase = mt * 128;
    int colBase = nt * 128;

    floatx4 acc[4][4] = {};

    int rA0 = tid >> 2, cA = tid & 3;   // rows 0..63
    int rA1 = rA0 + 64;                 // rows 64..127
    int pA0 = rA0 * 4 + (cA ^ ((rA0 >> 1) & 3));
    int pA1 = rA1 * 4 + (cA ^ ((rA1 >> 1) & 3));

    const char* pa0 = (const char*)(A  + (size_t)(rowBase + rA0) * Kp + cA * 8);
    const char* pa1 = (const char*)(A  + (size_t)(rowBase + rA1) * Kp + cA * 8);
    const char* pb0 = (const char*)(Bt + (size_t)(colBase + rA0) * Kp + cA * 8);
    const char* pb1 = (const char*)(Bt + (size_t)(colBase + rA1) * Kp + cA * 8);

    int posA[4], posB[4];
    #pragma unroll
    for (int t = 0; t < 4; ++t) {
        int rr = wm * 64 + t * 16 + l16;
        posA[t] = rr * 4 + (quad ^ ((rr >> 1) & 3));
    }
    #pragma unroll
    for (int u = 0; u < 4; ++u) {
        int cc = wn * 64 + u * 16 + l16;
        posB[u] = cc * 4 + (quad ^ ((cc >> 1) & 3));
    }

    int nK = Kp >> 5;
    float4 ra0 = *(const float4*)pa0;
    float4 ra1 = *(const float4*)pa1;
    float4 rb0 = *(const float4*)pb0;
    float4 rb1 = *(const float4*)pb1;

    for (int kt = 0; kt < nK; ++kt) {
        int buf = kt & 1;
        As[buf][pA0] = ra0;
        As[buf][pA1] = ra1;
        Bs[buf][pA0] = rb0;
        Bs[buf][pA1] = rb1;
        __syncthreads();
        if (kt + 1 < nK) {
            int off = (kt + 1) << 6;   // 32 bf16 = 64 bytes
            ra0 = *(const float4*)(pa0 + off);
            ra1 = *(const float4*)(pa1 + off);
            rb0 = *(const float4*)(pb0 + off);
            rb1 = *(const float4*)(pb1 + off);
        }
        short8 af[4], bf[4];
        #pragma unroll
        for (int t = 0; t < 4; ++t) af[t] = *(const short8*)(As[buf] + posA[t]);
        #pragma unroll
        for (int u = 0; u < 4; ++u) bf[u] = *(const short8*)(Bs[buf] + posB[u]);
        #pragma unroll
        for (int t = 0; t < 4; ++t)
            #pragma unroll
            for (int u = 0; u < 4; ++u)
                acc[t][u] = __builtin_amdgcn_mfma_f32_16x16x32_bf16(
                    af[t], bf[u], acc[t][u], 0, 0, 0);
        // no trailing barrier: next iter writes the other LDS buffer
    }

    if (!fuse) {
        #pragma unroll
        for (int u = 0; u < 4; ++u) {
            int col = colBase + wn * 64 + u * 16 + l16;
            float bc = 0.1f * bias[col];
            #pragma unroll
            for (int t = 0; t < 4; ++t) {
                int row0 = rowBase + wm * 64 + t * 16 + quad * 4;
                #pragma unroll
                for (int r = 0; r < 4; ++r) {
                    float x = alpha * acc[t][u][r] + bc;
                    float v = x / (1.f + expf(-x));
                    C[(size_t)(row0 + r) * UNITS + col] = __float2bfloat16(v);
                }
            }
        }
    } else {
        float rowsum[4][4] = {};
        #pragma unroll
        for (int u = 0; u < 4; ++u) {
            int col = colBase + wn * 64 + u * 16 + l16;
            float bc = 0.1f * bias[col];
            float w3c = w3[col] * a3;
            #pragma unroll
            for (int t = 0; t < 4; ++t)
                #pragma unroll
                for (int r = 0; r < 4; ++r) {
                    float x = alpha * acc[t][u][r] + bc;
                    float v = x / (1.f + expf(-x));
                    rowsum[t][r] += v * w3c;
                }
        }
        #pragma unroll
        for (int t = 0; t < 4; ++t)
            #pragma unroll
            for (int r = 0; r < 4; ++r) {
                float s = rowsum[t][r];
                s += __shfl_xor(s, 1, 64);
                s += __shfl_xor(s, 2, 64);
                s += __shfl_xor(s, 4, 64);
                s += __shfl_xor(s, 8, 64);
                rowsum[t][r] = s;
            }
        if (l16 == 0) {
            #pragma unroll
            for (int t = 0; t < 4; ++t) {
                int row0 = rowBase + wm * 64 + t * 16 + quad * 4;
                #pragma unroll
                for (int r = 0; r < 4; ++r) {
                    int row = row0 + r;
                    if (row < M && Zmask[row] > 0)
                        atomicAdd(&outacc[row], rowsum[t][r]);
                }
            }
        }
    }
}

static inline size_t align_up(size_t x, size_t a) { return (x + a - 1) & ~(a - 1); }

extern "C" void kernel_launch(void* const* d_in, const int* in_sizes, int n_in,
                              void* d_out, int out_size, void* d_ws, size_t ws_size,
                              hipStream_t stream)
{
    const float* R       = (const float*)d_in[0];
    const int*   Z       = (const int*)  d_in[1];
    const int*   nbr     = (const int*)  d_in[2];
    const float* offsets = (const float*)d_in[4];
    const float* emb     = (const float*)d_in[5];
    const float* W1      = (const float*)d_in[6];
    const float* b1      = (const float*)d_in[7];
    const float* W2      = (const float*)d_in[8];
    const float* b2      = (const float*)d_in[9];
    const float* W3      = (const float*)d_in[10];
    const float* b3      = (const float*)d_in[11];

    int natoms = in_sizes[0] / 3;
    int npairs = in_sizes[2] / 2;
    int Mpad = ((natoms + 127) / 128) * 128;
    int Mtiles = Mpad / 128;

    char* ws = (char*)d_ws;
    size_t off = 0;
    int* counts = (int*)(ws + off); off = align_up(off + natoms*4, 256);
    float* tmpRec = (float*)(ws + off); off = align_up(off + (size_t)natoms*CAP*8*4, 256);
    float* momG = (float*)(ws + off); off = align_up(off + (size_t)Mpad*100*4, 256);
    __hip_bfloat16* W1t   = (__hip_bfloat16*)(ws + off); off = align_up(off + (size_t)UNITS*KP1*2, 256);
    __hip_bfloat16* W2t   = (__hip_bfloat16*)(ws + off); off = align_up(off + (size_t)UNITS*UNITS*2, 256);
    __hip_bfloat16* feats = (__hip_bfloat16*)(ws + off); off = align_up(off + (size_t)Mpad*KP1*2, 256);
    __hip_bfloat16* h1    = (__hip_bfloat16*)(ws + off); off = align_up(off + (size_t)Mpad*UNITS*2, 256);

    // host-side double-precision basis constants (exact vs numpy reference)
    BasisConsts bc;
    {
        const double betta = 49.0 / 36.0;
        const double delta = 5.5 / 6.0;
        const double log2e = 1.4426950408889634073599246810;
        bc.f0k = (float)(-betta * log2e);
        bc.kg  = (float)(2.0 * betta * delta * log2e);
        for (int b = 0; b < 6; ++b)
            bc.c[b] = (float)exp(-betta * delta * (1.0 + delta * (2*b + 1)));
        bc.scale = (float)(pow(2.0 * betta / M_PI, 0.75) / sqrt(7.0));
    }

    int prepBlocks = 448 + (natoms + 255) / 256;
    prep_kernel<<<dim3(prepBlocks), 256, 0, stream>>>(
        W1, W2, W1t, W2t, counts, (float*)d_out, Z, b3, natoms);

    int pgrid = (npairs + 255) / 256;
    pair_compute_kernel<<<dim3(pgrid), 256, 0, stream>>>(
        R, Z, nbr, offsets, emb, counts, tmpRec, npairs, bc);

    moment_kernel<<<dim3(Mpad / 4), 256, 0, stream>>>(
        tmpRec, counts, momG, natoms);
    feat_kernel<<<dim3(Mpad / 64), 256, 0, stream>>>(momG, feats);

    float a1 = 1.0f / sqrtf((float)NFEAT);
    float a2 = 1.0f / sqrtf((float)UNITS);
    int gemmGrid = ((Mtiles + 7) / 8) * 8 * 4;
    gemm_mfma_swish<<<dim3(gemmGrid), 256, 0, stream>>>(
        feats, W1t, b1, h1, nullptr, nullptr, nullptr, KP1, natoms, Mtiles, a1, 0.f, 0);
    gemm_mfma_swish<<<dim3(gemmGrid), 256, 0, stream>>>(
        h1, W2t, b2, nullptr, W3, (float*)d_out, Z, UNITS, natoms, Mtiles, a2, a2, 1);
}

// Round 7
// 200.389 us; speedup vs baseline: 1.7512x; 1.0034x over previous
//
#include <hip/hip_runtime.h>
#include <hip/hip_bf16.h>
#include <cmath>

#define NSP 119
#define UNITS 512
#define NFEAT 360
#define KP1 384          // NFEAT padded to multiple of 32
#define CAP 128          // per-atom pair-segment capacity (mean ~21, >13 sigma)

typedef __attribute__((ext_vector_type(8))) short short8;
typedef __attribute__((ext_vector_type(4))) float floatx4;

#define AS1 __attribute__((address_space(1)))
#define AS3 __attribute__((address_space(3)))

// async global->LDS, 16B per lane; lds dest = wave-uniform base + lane*16
__device__ __forceinline__ void gload_lds16(const void* g, void* l) {
    __builtin_amdgcn_global_load_lds((AS1 void*)(size_t)g, (AS3 void*)l, 16, 0, 0);
}

// compile-time symmetric-index helpers (fold under full unroll)
__device__ __host__ constexpr int s2c(int i, int j) {
    return (i > j) ? i*(i+1)/2 + j : j*(j+1)/2 + i;
}
__device__ __host__ constexpr int s3c(int x, int y, int z) {
    int A = x > y ? x : y; A = A > z ? A : z;
    int C = x < y ? x : y; C = C < z ? C : z;
    int B = x + y + z - A - C;
    return A*(A+1)*(A+2)/6 + B*(B+1)/2 + C;
}

struct BasisConsts {
    float f0k;      // -betta * log2(e)
    float kg;       // 2*betta*delta*log2(e)
    float scale;    // rad_norm / sqrt(7)
    float c[6];     // exp(-betta*delta*(1 + delta*(2b+1)))
};

// ---------- phase 1 (fused): pair records + W transposes + out init ----------
// blocks [0, pgrid)            : pair compute -> per-atom segments
// blocks [pgrid, pgrid+448)    : W1/W2 tiled transpose to bf16
// blocks [pgrid+448, ...)      : out = (Z>0) ? 0.1*b3 : 0
// counts[] zeroed by hipMemsetAsync before this kernel.
__global__ __launch_bounds__(256) void pair_prep_kernel(
    const float* __restrict__ R, const int* __restrict__ Z,
    const int* __restrict__ nbr, const float* __restrict__ offsets,
    const float* __restrict__ emb, int* __restrict__ counts,
    float* __restrict__ tmpRec, int npairs, BasisConsts bc,
    const float* __restrict__ W1, const float* __restrict__ W2,
    __hip_bfloat16* __restrict__ W1t, __hip_bfloat16* __restrict__ W2t,
    float* __restrict__ outbuf, const float* __restrict__ b3,
    int pgrid, int natoms)
{
    int blk = blockIdx.x;
    if (blk >= pgrid) {
        int b = blk - pgrid;
        if (b < 448) {
            __shared__ float tile[32][33];
            const float* W; __hip_bfloat16* Wt; int K, Kp, ik, in;
            if (b < 192) { W = W1; Wt = W1t; K = NFEAT; Kp = KP1; ik = b % 12; in = b / 12; }
            else { int b2 = b - 192; W = W2; Wt = W2t; K = UNITS; Kp = UNITS; ik = b2 & 15; in = b2 >> 4; }
            int tx = threadIdx.x & 31, ty = threadIdx.x >> 5;
            int n = in * 32 + tx;                      // N = 512 for both matrices
            #pragma unroll
            for (int pp = 0; pp < 4; ++pp) {
                int kk = ty + pp * 8;
                int k = ik * 32 + kk;
                tile[kk][tx] = (k < K) ? W[(size_t)k * UNITS + n] : 0.f;
            }
            __syncthreads();
            #pragma unroll
            for (int pp = 0; pp < 4; ++pp) {
                int nn = ty + pp * 8;
                Wt[(size_t)(in * 32 + nn) * Kp + ik * 32 + tx] = __float2bfloat16(tile[tx][nn]);
            }
        } else {
            int idx = (b - 448) * 256 + threadIdx.x;
            if (idx < natoms)
                outbuf[idx] = (Z[idx] > 0) ? 0.1f * b3[0] : 0.f;
        }
        return;
    }

    int p = blk * 256 + threadIdx.x;
    if (p >= npairs) return;
    int i = nbr[p];
    int j = nbr[npairs + p];
    float dx = R[3*j]   - R[3*i]   + offsets[3*p];
    float dy = R[3*j+1] - R[3*i+1] + offsets[3*p+1];
    float dz = R[3*j+2] - R[3*i+2] + offsets[3*p+2];
    float dr2 = fmaf(dz, dz, fmaf(dy, dy, dx*dx));
    if (dr2 >= 36.0f) return;
    int pos = atomicAdd(&counts[i], 1);
    if (pos >= CAP) return;   // statistically impossible; memory-safety guard

    float dr  = sqrtf(dr2);
    float inv = 1.0f / (dr + 1e-5f);
    float d0  = dr - 0.5f;
    float basis[7];
    basis[0] = exp2f(bc.f0k * d0 * d0);
    float G  = exp2f(bc.kg * dr);
    float cur = basis[0];
    #pragma unroll
    for (int b = 0; b < 6; ++b) { cur *= G * bc.c[b]; basis[b+1] = cur; }
    float cut = 0.5f * (__cosf(dr * 0.52359877559829887f) + 1.0f);  // pi/R_MAX
    float s = bc.scale * cut;

    const float* e = emb + ((size_t)Z[j] * NSP + Z[i]) * 35;
    float ev[35];
    __builtin_memcpy(ev, e, 35 * sizeof(float));

    float rec[8];
    #pragma unroll
    for (int r = 0; r < 5; ++r) {
        float acc = 0.f;
        #pragma unroll
        for (int b = 0; b < 7; ++b) acc += ev[r*7+b] * basis[b];
        rec[r] = s * acc;
    }
    rec[5] = dx * inv; rec[6] = dy * inv; rec[7] = dz * inv;
    float4* out = (float4*)(tmpRec + ((size_t)i * CAP + pos) * 8);
    out[0] = make_float4(rec[0], rec[1], rec[2], rec[3]);
    out[1] = make_float4(rec[4], rec[5], rec[6], rec[7]);
}

// ---------- phase 2a: one wave per atom -> 100 compressed moments to global ----------
// Staged record (28 floats): [0..4]=rad, [5..24]=poly(1, dn, sym2[6], sym3[10]).
// momG blocked layout: momG[(a>>6)*6400 + e*64 + (a&63)], e = 0..99
#define SREC 28
__global__ __launch_bounds__(256) void moment_kernel(
    const float* __restrict__ tmpRec, const int* __restrict__ counts,
    float* __restrict__ momG, int natoms)
{
    int wv = threadIdx.x >> 6, lane = threadIdx.x & 63;
    int a = blockIdx.x * 4 + wv;
    __shared__ float stage[4][64][SREC];

    int cnt = 0;
    if (a < natoms) cnt = min(counts[a], CAP);   // pad atoms: zeros

    // lane -> (cr0, pk0) for moment element e = lane (0..63)
    int cr0, pk0;
    if (lane < 5)       { cr0 = lane;            pk0 = 0; }
    else if (lane < 20) { int c = lane - 5;      cr0 = c / 3;  pk0 = 1 + c % 3; }
    else if (lane < 50) { int c = lane - 20;     cr0 = c / 6;  pk0 = 4 + c % 6; }
    else                { int c = lane - 50;     cr0 = c / 10; pk0 = 10 + c % 10; }
    // lane -> (cr1, pk1) for element e = 64 + lane (lane < 36)
    int cr1 = 0, pk1 = 0;
    if (lane < 36) { int c = 14 + lane; cr1 = c / 10; pk1 = 10 + c % 10; }

    float acc0 = 0.f, acc1 = 0.f;
    for (int base = 0; base < cnt; base += 64) {
        int m = min(64, cnt - base);
        if (lane < m) {
            const float4* pd = (const float4*)(tmpRec + ((size_t)a * CAP + base + lane) * 8);
            float4 u = pd[0], v = pd[1];
            float x = v.y, y = v.z, z = v.w;
            float s2_0 = x*x, s2_1 = y*x, s2_2 = y*y, s2_3 = z*x, s2_4 = z*y, s2_5 = z*z;
            float* st = stage[wv][lane];
            ((float4*)st)[0] = u;                                    // rad0..3
            ((float4*)st)[1] = make_float4(v.x, 1.0f, x, y);         // rad4, p0=1, p1, p2
            ((float4*)st)[2] = make_float4(z, s2_0, s2_1, s2_2);     // p3..p6
            ((float4*)st)[3] = make_float4(s2_3, s2_4, s2_5, s2_0*x);// p7..p9, p10=xxx
            ((float4*)st)[4] = make_float4(s2_0*y, s2_2*x, s2_2*y, s2_0*z); // p11..p14
            ((float4*)st)[5] = make_float4(s2_1*z, s2_2*z, s2_5*x, s2_5*y); // p15..p18
            ((float4*)st)[6] = make_float4(s2_5*z, 0.f, 0.f, 0.f);   // p19, pad
        }
        __builtin_amdgcn_wave_barrier();
        for (int q = 0; q < m; ++q) {
            const float* s = stage[wv][q];
            acc0 += s[cr0] * s[5 + pk0];
            acc1 += s[cr1] * s[5 + pk1];
        }
        __builtin_amdgcn_wave_barrier();
    }
    size_t base = (size_t)(a >> 6) * 6400 + (size_t)(a & 63);
    momG[base + (size_t)lane * 64] = acc0;
    if (lane < 36) momG[base + (size_t)(64 + lane) * 64] = acc1;
}

// ---------- phase 2b: lane = atom, wave = feature group; all indices constexpr ----------
#define LROW 390   // LDS row stride in bf16: 195 words, 195%32=3 -> conflict-free
__global__ __launch_bounds__(256) void feat_kernel(
    const float* __restrict__ momG, __hip_bfloat16* __restrict__ feats)
{
    constexpr int cT2I[15] = {0,1,1,2,2,2,3,3,3,3,4,4,4,4,4};
    constexpr int cT2J[15] = {0,0,1,0,1,2,0,1,2,3,0,1,2,3,4};
    constexpr int cT3A[35] = {0, 1,1,1, 2,2,2,2,2,2, 3,3,3,3,3,3,3,3,3,3, 4,4,4,4,4,4,4,4,4,4,4,4,4,4,4};
    constexpr int cT3B[35] = {0, 0,1,1, 0,1,1,2,2,2, 0,1,1,2,2,2,3,3,3,3, 0,1,1,2,2,2,3,3,3,3,4,4,4,4,4};
    constexpr int cT3C[35] = {0, 0,0,1, 0,0,1,0,1,2, 0,0,1,0,1,2,0,1,2,3, 0,0,1,0,1,2,0,1,2,3,0,1,2,3,4};
    constexpr float cW2[6]  = {1.f,2.f,1.f,2.f,2.f,1.f};
    constexpr float cW3[10] = {1.f,3.f,3.f,1.f,3.f,6.f,3.f,3.f,3.f,1.f};

    __shared__ __hip_bfloat16 ldsF[64][LROW];
    int wv = threadIdx.x >> 6, lane = threadIdx.x & 63;
    const float* mg = momG + (size_t)blockIdx.x * 6400 + lane;

    #define LDM(e) mg[(e) * 64]
    #define STF(f, v) ldsF[lane][(f)] = __float2bfloat16(v)

    if (wv == 0) {
        // c6 for p = 0..9  -> feats 160 + p*5 + t
        float m3[50], m2[30];
        #pragma unroll
        for (int e = 0; e < 50; ++e) m3[e] = LDM(50 + e);
        #pragma unroll
        for (int e = 0; e < 30; ++e) m2[e] = LDM(20 + e);
        #pragma unroll
        for (int p = 0; p < 10; ++p) {
            int r = cT2I[p], s = cT2J[p];
            float B2v[9];
            #pragma unroll
            for (int z = 0; z < 3; ++z)
                #pragma unroll
                for (int w = 0; w < 3; ++w) {
                    float acc = 0.f;
                    #pragma unroll
                    for (int x = 0; x < 3; ++x)
                        #pragma unroll
                        for (int y = 0; y < 3; ++y)
                            acc += m3[r*10 + s3c(x,y,z)] * m3[s*10 + s3c(x,y,w)];
                    B2v[z*3+w] = acc;
                }
            #pragma unroll
            for (int t = 0; t < 5; ++t) {
                float acc = 0.f;
                #pragma unroll
                for (int z = 0; z < 3; ++z)
                    #pragma unroll
                    for (int w = 0; w < 3; ++w)
                        acc += B2v[z*3+w] * m2[t*6 + s2c(z,w)];
                STF(160 + p*5 + t, acc);
            }
        }
    } else if (wv == 1) {
        // M0, c1, c2, c4, zero-pad
        float m0[5], m1[15], m2[30];
        #pragma unroll
        for (int e = 0; e < 5; ++e)  m0[e] = LDM(e);
        #pragma unroll
        for (int e = 0; e < 15; ++e) m1[e] = LDM(5 + e);
        #pragma unroll
        for (int e = 0; e < 30; ++e) m2[e] = LDM(20 + e);
        #pragma unroll
        for (int r = 0; r < 5; ++r) STF(r, m0[r]);
        #pragma unroll
        for (int p = 0; p < 15; ++p) {
            int r = cT2I[p], s = cT2J[p];
            float v1 = m1[r*3]*m1[s*3] + m1[r*3+1]*m1[s*3+1] + m1[r*3+2]*m1[s*3+2];
            STF(5 + p, v1);
            float v2 = 0.f;
            #pragma unroll
            for (int k = 0; k < 6; ++k) v2 += cW2[k] * m2[r*6+k] * m2[s*6+k];
            STF(20 + p, v2);
        }
        #pragma unroll
        for (int q = 0; q < 35; ++q) {
            int r = cT3A[q], s = cT3B[q], t = cT3C[q];
            float v = 0.f;
            #pragma unroll
            for (int x = 0; x < 3; ++x)
                #pragma unroll
                for (int y = 0; y < 3; ++y) {
                    float d = 0.f;
                    #pragma unroll
                    for (int z = 0; z < 3; ++z)
                        d += m2[s*6 + s2c(x,z)] * m2[t*6 + s2c(y,z)];
                    v += m2[r*6 + s2c(x,y)] * d;
                }
            STF(50 + q, v);
        }
        #pragma unroll
        for (int f = NFEAT; f < KP1; ++f) STF(f, 0.f);
    } else if (wv == 2) {
        // c6 for p = 10..14, plus all of c5
        float m1[15], m2[30], m3[50];
        #pragma unroll
        for (int e = 0; e < 15; ++e) m1[e] = LDM(5 + e);
        #pragma unroll
        for (int e = 0; e < 30; ++e) m2[e] = LDM(20 + e);
        #pragma unroll
        for (int e = 0; e < 50; ++e) m3[e] = LDM(50 + e);
        #pragma unroll
        for (int p = 10; p < 15; ++p) {
            int r = cT2I[p], s = cT2J[p];
            float B2v[9];
            #pragma unroll
            for (int z = 0; z < 3; ++z)
                #pragma unroll
                for (int w = 0; w < 3; ++w) {
                    float acc = 0.f;
                    #pragma unroll
                    for (int x = 0; x < 3; ++x)
                        #pragma unroll
                        for (int y = 0; y < 3; ++y)
                            acc += m3[r*10 + s3c(x,y,z)] * m3[s*10 + s3c(x,y,w)];
                    B2v[z*3+w] = acc;
                }
            #pragma unroll
            for (int t = 0; t < 5; ++t) {
                float acc = 0.f;
                #pragma unroll
                for (int z = 0; z < 3; ++z)
                    #pragma unroll
                    for (int w = 0; w < 3; ++w)
                        acc += B2v[z*3+w] * m2[t*6 + s2c(z,w)];
                STF(160 + p*5 + t, acc);
            }
        }
        #pragma unroll
        for (int p = 0; p < 15; ++p) {
            int r = cT2I[p], s = cT2J[p];
            float o[9];
            #pragma unroll
            for (int x = 0; x < 3; ++x)
                #pragma unroll
                for (int y = 0; y < 3; ++y) o[x*3+y] = m1[r*3+x] * m1[s*3+y];
            #pragma unroll
            for (int t = 0; t < 5; ++t) {
                float v = 0.f;
                #pragma unroll
                for (int x = 0; x < 3; ++x)
                    #pragma unroll
                    for (int y = 0; y < 3; ++y)
                        v += o[x*3+y] * m2[t*6 + s2c(x,y)];
                STF(85 + p*5 + t, v);
            }
        }
    } else {
        // c3, c7
        float m1[15], m2[30], m3[50];
        #pragma unroll
        for (int e = 0; e < 15; ++e) m1[e] = LDM(5 + e);
        #pragma unroll
        for (int e = 0; e < 30; ++e) m2[e] = LDM(20 + e);
        #pragma unroll
        for (int e = 0; e < 50; ++e) m3[e] = LDM(50 + e);
        #pragma unroll
        for (int p = 0; p < 15; ++p) {
            int r = cT2I[p], s = cT2J[p];
            float v = 0.f;
            #pragma unroll
            for (int k = 0; k < 10; ++k) v += cW3[k] * m3[r*10+k] * m3[s*10+k];
            STF(35 + p, v);
        }
        #pragma unroll
        for (int r = 0; r < 5; ++r)
            #pragma unroll
            for (int s = 0; s < 5; ++s) {
                float A3z[3];
                #pragma unroll
                for (int z = 0; z < 3; ++z) {
                    float v = 0.f;
                    #pragma unroll
                    for (int x = 0; x < 3; ++x)
                        #pragma unroll
                        for (int y = 0; y < 3; ++y)
                            v += m3[r*10 + s3c(x,y,z)] * m2[s*6 + s2c(x,y)];
                    A3z[z] = v;
                }
                #pragma unroll
                for (int t = 0; t < 5; ++t) {
                    float v = A3z[0]*m1[t*3] + A3z[1]*m1[t*3+1] + A3z[2]*m1[t*3+2];
                    STF(235 + r*25 + s*5 + t, v);
                }
            }
    }
    __syncthreads();

    // coalesced copy-out: wave wv handles rows wv*16 .. wv*16+15
    __hip_bfloat16* dst = feats + (size_t)blockIdx.x * 64 * KP1;
    #pragma unroll
    for (int rr = 0; rr < 16; ++rr) {
        int row = wv * 16 + rr;
        #pragma unroll
        for (int it = 0; it < 3; ++it) {
            uint32_t v = *(const uint32_t*)&ldsF[row][(it*64 + lane)*2];
            *(uint32_t*)&dst[(size_t)row * KP1 + (size_t)(it*64 + lane)*2] = v;
        }
    }
    #undef LDM
    #undef STF
}

// ---------- bf16 MFMA GEMM, 128x128 tile, BK=32, global_load_lds staging ----------
// LDS dest is LINEAR (slot s = tid + 256h -> offset s*16); the XOR swizzle is
// applied to the GLOBAL source chunk instead (inverse-swz source, m173 pattern):
// LDS[r*4+c] = global[r][c ^ swz(r)], readers use pos = r*4 + (q ^ swz(r)).
// 1D grid with XCD-grouped swizzle: mt = (bid>>5)*8 + (bid&7), nt = (bid>>3)&3.
__global__ __launch_bounds__(256) void gemm_mfma_swish(
    const __hip_bfloat16* __restrict__ A, const __hip_bfloat16* __restrict__ Bt,
    const float* __restrict__ bias, __hip_bfloat16* __restrict__ C,
    const float* __restrict__ w3, float* __restrict__ outacc,
    const int* __restrict__ Zmask,
    int Kp, int M, int Mtiles, float alpha, float a3, int fuse)
{
    __shared__ float4 As[2][512];   // 128 rows x 4 chunks (32 bf16/row)
    __shared__ float4 Bs[2][512];   // 128 rows x 4 chunks
    int tid = threadIdx.x;
    int wave = tid >> 6, lane = tid & 63;
    int quad = lane >> 4, l16 = lane & 15;
    int wm = wave >> 1, wn = wave & 1;   // 2x2 waves: 64-row x 64-col each
    int bid = blockIdx.x;
    int mt = (bid >> 5) * 8 + (bid & 7);
    int nt = (bid >> 3) & 3;
    if (mt >= Mtiles) return;
    int rowBase = mt * 128;
    int colBase = nt * 128;

    floatx4 acc[4][4] = {};

    // staging slots: s0 = tid (rows 0..63), s1 = tid+256 (rows 64..127)
    int r0 = tid >> 2, c0 = (tid & 3) ^ ((r0 >> 1) & 3);
    int r1 = r0 + 64,  c1 = (tid & 3) ^ ((r1 >> 1) & 3);

    const char* gA0 = (const char*)A  + ((size_t)(rowBase + r0) * Kp) * 2 + c0 * 16;
    const char* gA1 = (const char*)A  + ((size_t)(rowBase + r1) * Kp) * 2 + c1 * 16;
    const char* gB0 = (const char*)Bt + ((size_t)(colBase + r0) * Kp) * 2 + c0 * 16;
    const char* gB1 = (const char*)Bt + ((size_t)(colBase + r1) * Kp) * 2 + c1 * 16;

    char* lA = (char*)As;
    char* lB = (char*)Bs;
    int wvoff = wave << 10;          // wave-uniform LDS base offset

    int posA[4], posB[4];
    #pragma unroll
    for (int t = 0; t < 4; ++t) {
        int rr = wm * 64 + t * 16 + l16;
        posA[t] = rr * 4 + (quad ^ ((rr >> 1) & 3));
    }
    #pragma unroll
    for (int u = 0; u < 4; ++u) {
        int cc = wn * 64 + u * 16 + l16;
        posB[u] = cc * 4 + (quad ^ ((cc >> 1) & 3));
    }

    int nK = Kp >> 5;

    // prologue: stage K-tile 0 into buffer 0
    {
        int lo = wvoff;
        gload_lds16(gA0, lA + lo);
        gload_lds16(gA1, lA + lo + 4096);
        gload_lds16(gB0, lB + lo);
        gload_lds16(gB1, lB + lo + 4096);
    }
    __syncthreads();

    for (int kt = 0; kt < nK; ++kt) {
        int buf = kt & 1;
        if (kt + 1 < nK) {
            int go = (kt + 1) << 6;                 // 32 bf16 = 64 bytes
            int lo = ((buf ^ 1) << 13) + wvoff;     // other buffer
            gload_lds16(gA0 + go, lA + lo);
            gload_lds16(gA1 + go, lA + lo + 4096);
            gload_lds16(gB0 + go, lB + lo);
            gload_lds16(gB1 + go, lB + lo + 4096);
        }
        short8 af[4], bf[4];
        #pragma unroll
        for (int t = 0; t < 4; ++t) af[t] = *(const short8*)(As[buf] + posA[t]);
        #pragma unroll
        for (int u = 0; u < 4; ++u) bf[u] = *(const short8*)(Bs[buf] + posB[u]);
        #pragma unroll
        for (int t = 0; t < 4; ++t)
            #pragma unroll
            for (int u = 0; u < 4; ++u)
                acc[t][u] = __builtin_amdgcn_mfma_f32_16x16x32_bf16(
                    af[t], bf[u], acc[t][u], 0, 0, 0);
        // barrier: (a) all lanes done reading buf, (b) drains vmcnt so the
        // staged buf^1 is complete before next iteration reads it.
        __syncthreads();
    }

    if (!fuse) {
        #pragma unroll
        for (int u = 0; u < 4; ++u) {
            int col = colBase + wn * 64 + u * 16 + l16;
            float bc = 0.1f * bias[col];
            #pragma unroll
            for (int t = 0; t < 4; ++t) {
                int row0 = rowBase + wm * 64 + t * 16 + quad * 4;
                #pragma unroll
                for (int r = 0; r < 4; ++r) {
                    float x = alpha * acc[t][u][r] + bc;
                    float v = x / (1.f + expf(-x));
                    C[(size_t)(row0 + r) * UNITS + col] = __float2bfloat16(v);
                }
            }
        }
    } else {
        float rowsum[4][4] = {};
        #pragma unroll
        for (int u = 0; u < 4; ++u) {
            int col = colBase + wn * 64 + u * 16 + l16;
            float bc = 0.1f * bias[col];
            float w3c = w3[col] * a3;
            #pragma unroll
            for (int t = 0; t < 4; ++t)
                #pragma unroll
                for (int r = 0; r < 4; ++r) {
                    float x = alpha * acc[t][u][r] + bc;
                    float v = x / (1.f + expf(-x));
                    rowsum[t][r] += v * w3c;
                }
        }
        #pragma unroll
        for (int t = 0; t < 4; ++t)
            #pragma unroll
            for (int r = 0; r < 4; ++r) {
                float s = rowsum[t][r];
                s += __shfl_xor(s, 1, 64);
                s += __shfl_xor(s, 2, 64);
                s += __shfl_xor(s, 4, 64);
                s += __shfl_xor(s, 8, 64);
                rowsum[t][r] = s;
            }
        if (l16 == 0) {
            #pragma unroll
            for (int t = 0; t < 4; ++t) {
                int row0 = rowBase + wm * 64 + t * 16 + quad * 4;
                #pragma unroll
                for (int r = 0; r < 4; ++r) {
                    int row = row0 + r;
                    if (row < M && Zmask[row] > 0)
                        atomicAdd(&outacc[row], rowsum[t][r]);
                }
            }
        }
    }
}

static inline size_t align_up(size_t x, size_t a) { return (x + a - 1) & ~(a - 1); }

extern "C" void kernel_launch(void* const* d_in, const int* in_sizes, int n_in,
                              void* d_out, int out_size, void* d_ws, size_t ws_size,
                              hipStream_t stream)
{
    const float* R       = (const float*)d_in[0];
    const int*   Z       = (const int*)  d_in[1];
    const int*   nbr     = (const int*)  d_in[2];
    const float* offsets = (const float*)d_in[4];
    const float* emb     = (const float*)d_in[5];
    const float* W1      = (const float*)d_in[6];
    const float* b1      = (const float*)d_in[7];
    const float* W2      = (const float*)d_in[8];
    const float* b2      = (const float*)d_in[9];
    const float* W3      = (const float*)d_in[10];
    const float* b3      = (const float*)d_in[11];

    int natoms = in_sizes[0] / 3;
    int npairs = in_sizes[2] / 2;
    int Mpad = ((natoms + 127) / 128) * 128;
    int Mtiles = Mpad / 128;

    char* ws = (char*)d_ws;
    size_t off = 0;
    int* counts = (int*)(ws + off); off = align_up(off + natoms*4, 256);
    float* tmpRec = (float*)(ws + off); off = align_up(off + (size_t)natoms*CAP*8*4, 256);
    float* momG = (float*)(ws + off); off = align_up(off + (size_t)Mpad*100*4, 256);
    __hip_bfloat16* W1t   = (__hip_bfloat16*)(ws + off); off = align_up(off + (size_t)UNITS*KP1*2, 256);
    __hip_bfloat16* W2t   = (__hip_bfloat16*)(ws + off); off = align_up(off + (size_t)UNITS*UNITS*2, 256);
    __hip_bfloat16* feats = (__hip_bfloat16*)(ws + off); off = align_up(off + (size_t)Mpad*KP1*2, 256);
    __hip_bfloat16* h1    = (__hip_bfloat16*)(ws + off); off = align_up(off + (size_t)Mpad*UNITS*2, 256);

    // host-side double-precision basis constants (exact vs numpy reference)
    BasisConsts bc;
    {
        const double betta = 49.0 / 36.0;
        const double delta = 5.5 / 6.0;
        const double log2e = 1.4426950408889634073599246810;
        bc.f0k = (float)(-betta * log2e);
        bc.kg  = (float)(2.0 * betta * delta * log2e);
        for (int b = 0; b < 6; ++b)
            bc.c[b] = (float)exp(-betta * delta * (1.0 + delta * (2*b + 1)));
        bc.scale = (float)(pow(2.0 * betta / M_PI, 0.75) / sqrt(7.0));
    }

    hipMemsetAsync(counts, 0, (size_t)natoms * sizeof(int), stream);

    int pgrid = (npairs + 255) / 256;
    int totalBlocks = pgrid + 448 + (natoms + 255) / 256;
    pair_prep_kernel<<<dim3(totalBlocks), 256, 0, stream>>>(
        R, Z, nbr, offsets, emb, counts, tmpRec, npairs, bc,
        W1, W2, W1t, W2t, (float*)d_out, b3, pgrid, natoms);

    moment_kernel<<<dim3(Mpad / 4), 256, 0, stream>>>(
        tmpRec, counts, momG, natoms);
    feat_kernel<<<dim3(Mpad / 64), 256, 0, stream>>>(momG, feats);

    float a1 = 1.0f / sqrtf((float)NFEAT);
    float a2 = 1.0f / sqrtf((float)UNITS);
    int gemmGrid = ((Mtiles + 7) / 8) * 8 * 4;
    gemm_mfma_swish<<<dim3(gemmGrid), 256, 0, stream>>>(
        feats, W1t, b1, h1, nullptr, nullptr, nullptr, KP1, natoms, Mtiles, a1, 0.f, 0);
    gemm_mfma_swish<<<dim3(gemmGrid), 256, 0, stream>>>(
        h1, W2t, b2, nullptr, W3, (float*)d_out, Z, UNITS, natoms, Mtiles, a2, a2, 1);
}

// Round 8
// 195.570 us; speedup vs baseline: 1.7944x; 1.0246x over previous
//
#include <hip/hip_runtime.h>
#include <hip/hip_bf16.h>
#include <cmath>

#define NSP 119
#define UNITS 512
#define NFEAT 360
#define KP1 384          // NFEAT padded to multiple of 32
#define CAP 128          // per-atom pair-segment capacity (mean ~21, >13 sigma)

typedef __attribute__((ext_vector_type(8))) short short8;
typedef __attribute__((ext_vector_type(4))) float floatx4;

#define AS1 __attribute__((address_space(1)))
#define AS3 __attribute__((address_space(3)))

// async global->LDS, 16B per lane; lds dest = wave-uniform base + lane*16
__device__ __forceinline__ void gload_lds16(const void* g, void* l) {
    __builtin_amdgcn_global_load_lds((AS1 void*)(size_t)g, (AS3 void*)l, 16, 0, 0);
}

// compile-time symmetric-index helpers (fold under full unroll)
__device__ __host__ constexpr int s2c(int i, int j) {
    return (i > j) ? i*(i+1)/2 + j : j*(j+1)/2 + i;
}
__device__ __host__ constexpr int s3c(int x, int y, int z) {
    int A = x > y ? x : y; A = A > z ? A : z;
    int C = x < y ? x : y; C = C < z ? C : z;
    int B = x + y + z - A - C;
    return A*(A+1)*(A+2)/6 + B*(B+1)/2 + C;
}

struct BasisConsts {
    float f0k;      // -betta * log2(e)
    float kg;       // 2*betta*delta*log2(e)
    float scale;    // rad_norm / sqrt(7)
    float c[6];     // exp(-betta*delta*(1 + delta*(2b+1)))
};

// ---------- phase 1 (fused): pair records + W transposes + out init ----------
// blocks [0, pgrid)            : pair compute -> per-atom segments
// blocks [pgrid, pgrid+448)    : W1/W2 tiled transpose to bf16
// blocks [pgrid+448, ...)      : out = (Z>0) ? 0.1*b3 : 0
// counts[] zeroed by hipMemsetAsync before this kernel.
__global__ __launch_bounds__(256) void pair_prep_kernel(
    const float* __restrict__ R, const int* __restrict__ Z,
    const int* __restrict__ nbr, const float* __restrict__ offsets,
    const float* __restrict__ emb, int* __restrict__ counts,
    float* __restrict__ tmpRec, int npairs, BasisConsts bc,
    const float* __restrict__ W1, const float* __restrict__ W2,
    __hip_bfloat16* __restrict__ W1t, __hip_bfloat16* __restrict__ W2t,
    float* __restrict__ outbuf, const float* __restrict__ b3,
    int pgrid, int natoms)
{
    int blk = blockIdx.x;
    if (blk >= pgrid) {
        int b = blk - pgrid;
        if (b < 448) {
            __shared__ float tile[32][33];
            const float* W; __hip_bfloat16* Wt; int K, Kp, ik, in;
            if (b < 192) { W = W1; Wt = W1t; K = NFEAT; Kp = KP1; ik = b % 12; in = b / 12; }
            else { int b2 = b - 192; W = W2; Wt = W2t; K = UNITS; Kp = UNITS; ik = b2 & 15; in = b2 >> 4; }
            int tx = threadIdx.x & 31, ty = threadIdx.x >> 5;
            int n = in * 32 + tx;                      // N = 512 for both matrices
            #pragma unroll
            for (int pp = 0; pp < 4; ++pp) {
                int kk = ty + pp * 8;
                int k = ik * 32 + kk;
                tile[kk][tx] = (k < K) ? W[(size_t)k * UNITS + n] : 0.f;
            }
            __syncthreads();
            #pragma unroll
            for (int pp = 0; pp < 4; ++pp) {
                int nn = ty + pp * 8;
                Wt[(size_t)(in * 32 + nn) * Kp + ik * 32 + tx] = __float2bfloat16(tile[tx][nn]);
            }
        } else {
            int idx = (b - 448) * 256 + threadIdx.x;
            if (idx < natoms)
                outbuf[idx] = (Z[idx] > 0) ? 0.1f * b3[0] : 0.f;
        }
        return;
    }

    int p = blk * 256 + threadIdx.x;
    if (p >= npairs) return;
    int i = nbr[p];
    int j = nbr[npairs + p];
    float dx = R[3*j]   - R[3*i]   + offsets[3*p];
    float dy = R[3*j+1] - R[3*i+1] + offsets[3*p+1];
    float dz = R[3*j+2] - R[3*i+2] + offsets[3*p+2];
    float dr2 = fmaf(dz, dz, fmaf(dy, dy, dx*dx));
    if (dr2 >= 36.0f) return;
    int pos = atomicAdd(&counts[i], 1);
    if (pos >= CAP) return;   // statistically impossible; memory-safety guard

    float dr  = sqrtf(dr2);
    float inv = 1.0f / (dr + 1e-5f);
    float d0  = dr - 0.5f;
    float basis[7];
    basis[0] = exp2f(bc.f0k * d0 * d0);
    float G  = exp2f(bc.kg * dr);
    float cur = basis[0];
    #pragma unroll
    for (int b = 0; b < 6; ++b) { cur *= G * bc.c[b]; basis[b+1] = cur; }
    float cut = 0.5f * (__cosf(dr * 0.52359877559829887f) + 1.0f);  // pi/R_MAX
    float s = bc.scale * cut;

    const float* e = emb + ((size_t)Z[j] * NSP + Z[i]) * 35;
    float ev[35];
    __builtin_memcpy(ev, e, 35 * sizeof(float));

    float rec[8];
    #pragma unroll
    for (int r = 0; r < 5; ++r) {
        float acc = 0.f;
        #pragma unroll
        for (int b = 0; b < 7; ++b) acc += ev[r*7+b] * basis[b];
        rec[r] = s * acc;
    }
    rec[5] = dx * inv; rec[6] = dy * inv; rec[7] = dz * inv;
    float4* out = (float4*)(tmpRec + ((size_t)i * CAP + pos) * 8);
    out[0] = make_float4(rec[0], rec[1], rec[2], rec[3]);
    out[1] = make_float4(rec[4], rec[5], rec[6], rec[7]);
}

// ---------- phase 2a: one wave per atom -> 100 compressed moments to global ----------
// Staged record (28 floats): [0..4]=rad, [5..24]=poly(1, dn, sym2[6], sym3[10]).
// momG blocked layout: momG[(a>>6)*6400 + e*64 + (a&63)], e = 0..99
#define SREC 28
__global__ __launch_bounds__(256) void moment_kernel(
    const float* __restrict__ tmpRec, const int* __restrict__ counts,
    float* __restrict__ momG, int natoms)
{
    int wv = threadIdx.x >> 6, lane = threadIdx.x & 63;
    int a = blockIdx.x * 4 + wv;
    __shared__ float stage[4][64][SREC];

    int cnt = 0;
    if (a < natoms) cnt = min(counts[a], CAP);   // pad atoms: zeros

    // lane -> (cr0, pk0) for moment element e = lane (0..63)
    int cr0, pk0;
    if (lane < 5)       { cr0 = lane;            pk0 = 0; }
    else if (lane < 20) { int c = lane - 5;      cr0 = c / 3;  pk0 = 1 + c % 3; }
    else if (lane < 50) { int c = lane - 20;     cr0 = c / 6;  pk0 = 4 + c % 6; }
    else                { int c = lane - 50;     cr0 = c / 10; pk0 = 10 + c % 10; }
    // lane -> (cr1, pk1) for element e = 64 + lane (lane < 36)
    int cr1 = 0, pk1 = 0;
    if (lane < 36) { int c = 14 + lane; cr1 = c / 10; pk1 = 10 + c % 10; }

    float acc0 = 0.f, acc1 = 0.f;
    for (int base = 0; base < cnt; base += 64) {
        int m = min(64, cnt - base);
        if (lane < m) {
            const float4* pd = (const float4*)(tmpRec + ((size_t)a * CAP + base + lane) * 8);
            float4 u = pd[0], v = pd[1];
            float x = v.y, y = v.z, z = v.w;
            float s2_0 = x*x, s2_1 = y*x, s2_2 = y*y, s2_3 = z*x, s2_4 = z*y, s2_5 = z*z;
            float* st = stage[wv][lane];
            ((float4*)st)[0] = u;                                    // rad0..3
            ((float4*)st)[1] = make_float4(v.x, 1.0f, x, y);         // rad4, p0=1, p1, p2
            ((float4*)st)[2] = make_float4(z, s2_0, s2_1, s2_2);     // p3..p6
            ((float4*)st)[3] = make_float4(s2_3, s2_4, s2_5, s2_0*x);// p7..p9, p10=xxx
            ((float4*)st)[4] = make_float4(s2_0*y, s2_2*x, s2_2*y, s2_0*z); // p11..p14
            ((float4*)st)[5] = make_float4(s2_1*z, s2_2*z, s2_5*x, s2_5*y); // p15..p18
            ((float4*)st)[6] = make_float4(s2_5*z, 0.f, 0.f, 0.f);   // p19, pad
        }
        __builtin_amdgcn_wave_barrier();
        for (int q = 0; q < m; ++q) {
            const float* s = stage[wv][q];
            acc0 += s[cr0] * s[5 + pk0];
            acc1 += s[cr1] * s[5 + pk1];
        }
        __builtin_amdgcn_wave_barrier();
    }
    size_t base = (size_t)(a >> 6) * 6400 + (size_t)(a & 63);
    momG[base + (size_t)lane * 64] = acc0;
    if (lane < 36) momG[base + (size_t)(64 + lane) * 64] = acc1;
}

// ---------- phase 2b: lane = atom, wave = feature group; all indices constexpr ----------
#define LROW 390   // LDS row stride in bf16: 195 words, 195%32=3 -> conflict-free
__global__ __launch_bounds__(256) void feat_kernel(
    const float* __restrict__ momG, __hip_bfloat16* __restrict__ feats)
{
    constexpr int cT2I[15] = {0,1,1,2,2,2,3,3,3,3,4,4,4,4,4};
    constexpr int cT2J[15] = {0,0,1,0,1,2,0,1,2,3,0,1,2,3,4};
    constexpr int cT3A[35] = {0, 1,1,1, 2,2,2,2,2,2, 3,3,3,3,3,3,3,3,3,3, 4,4,4,4,4,4,4,4,4,4,4,4,4,4,4};
    constexpr int cT3B[35] = {0, 0,1,1, 0,1,1,2,2,2, 0,1,1,2,2,2,3,3,3,3, 0,1,1,2,2,2,3,3,3,3,4,4,4,4,4};
    constexpr int cT3C[35] = {0, 0,0,1, 0,0,1,0,1,2, 0,0,1,0,1,2,0,1,2,3, 0,0,1,0,1,2,0,1,2,3,0,1,2,3,4};
    constexpr float cW2[6]  = {1.f,2.f,1.f,2.f,2.f,1.f};
    constexpr float cW3[10] = {1.f,3.f,3.f,1.f,3.f,6.f,3.f,3.f,3.f,1.f};

    __shared__ __hip_bfloat16 ldsF[64][LROW];
    int wv = threadIdx.x >> 6, lane = threadIdx.x & 63;
    const float* mg = momG + (size_t)blockIdx.x * 6400 + lane;

    #define LDM(e) mg[(e) * 64]
    #define STF(f, v) ldsF[lane][(f)] = __float2bfloat16(v)

    if (wv == 0) {
        // c6 for p = 0..9  -> feats 160 + p*5 + t
        float m3[50], m2[30];
        #pragma unroll
        for (int e = 0; e < 50; ++e) m3[e] = LDM(50 + e);
        #pragma unroll
        for (int e = 0; e < 30; ++e) m2[e] = LDM(20 + e);
        #pragma unroll
        for (int p = 0; p < 10; ++p) {
            int r = cT2I[p], s = cT2J[p];
            float B2v[9];
            #pragma unroll
            for (int z = 0; z < 3; ++z)
                #pragma unroll
                for (int w = 0; w < 3; ++w) {
                    float acc = 0.f;
                    #pragma unroll
                    for (int x = 0; x < 3; ++x)
                        #pragma unroll
                        for (int y = 0; y < 3; ++y)
                            acc += m3[r*10 + s3c(x,y,z)] * m3[s*10 + s3c(x,y,w)];
                    B2v[z*3+w] = acc;
                }
            #pragma unroll
            for (int t = 0; t < 5; ++t) {
                float acc = 0.f;
                #pragma unroll
                for (int z = 0; z < 3; ++z)
                    #pragma unroll
                    for (int w = 0; w < 3; ++w)
                        acc += B2v[z*3+w] * m2[t*6 + s2c(z,w)];
                STF(160 + p*5 + t, acc);
            }
        }
    } else if (wv == 1) {
        // M0, c1, c2, c4, zero-pad
        float m0[5], m1[15], m2[30];
        #pragma unroll
        for (int e = 0; e < 5; ++e)  m0[e] = LDM(e);
        #pragma unroll
        for (int e = 0; e < 15; ++e) m1[e] = LDM(5 + e);
        #pragma unroll
        for (int e = 0; e < 30; ++e) m2[e] = LDM(20 + e);
        #pragma unroll
        for (int r = 0; r < 5; ++r) STF(r, m0[r]);
        #pragma unroll
        for (int p = 0; p < 15; ++p) {
            int r = cT2I[p], s = cT2J[p];
            float v1 = m1[r*3]*m1[s*3] + m1[r*3+1]*m1[s*3+1] + m1[r*3+2]*m1[s*3+2];
            STF(5 + p, v1);
            float v2 = 0.f;
            #pragma unroll
            for (int k = 0; k < 6; ++k) v2 += cW2[k] * m2[r*6+k] * m2[s*6+k];
            STF(20 + p, v2);
        }
        #pragma unroll
        for (int q = 0; q < 35; ++q) {
            int r = cT3A[q], s = cT3B[q], t = cT3C[q];
            float v = 0.f;
            #pragma unroll
            for (int x = 0; x < 3; ++x)
                #pragma unroll
                for (int y = 0; y < 3; ++y) {
                    float d = 0.f;
                    #pragma unroll
                    for (int z = 0; z < 3; ++z)
                        d += m2[s*6 + s2c(x,z)] * m2[t*6 + s2c(y,z)];
                    v += m2[r*6 + s2c(x,y)] * d;
                }
            STF(50 + q, v);
        }
        #pragma unroll
        for (int f = NFEAT; f < KP1; ++f) STF(f, 0.f);
    } else if (wv == 2) {
        // c6 for p = 10..14, plus all of c5
        float m1[15], m2[30], m3[50];
        #pragma unroll
        for (int e = 0; e < 15; ++e) m1[e] = LDM(5 + e);
        #pragma unroll
        for (int e = 0; e < 30; ++e) m2[e] = LDM(20 + e);
        #pragma unroll
        for (int e = 0; e < 50; ++e) m3[e] = LDM(50 + e);
        #pragma unroll
        for (int p = 10; p < 15; ++p) {
            int r = cT2I[p], s = cT2J[p];
            float B2v[9];
            #pragma unroll
            for (int z = 0; z < 3; ++z)
                #pragma unroll
                for (int w = 0; w < 3; ++w) {
                    float acc = 0.f;
                    #pragma unroll
                    for (int x = 0; x < 3; ++x)
                        #pragma unroll
                        for (int y = 0; y < 3; ++y)
                            acc += m3[r*10 + s3c(x,y,z)] * m3[s*10 + s3c(x,y,w)];
                    B2v[z*3+w] = acc;
                }
            #pragma unroll
            for (int t = 0; t < 5; ++t) {
                float acc = 0.f;
                #pragma unroll
                for (int z = 0; z < 3; ++z)
                    #pragma unroll
                    for (int w = 0; w < 3; ++w)
                        acc += B2v[z*3+w] * m2[t*6 + s2c(z,w)];
                STF(160 + p*5 + t, acc);
            }
        }
        #pragma unroll
        for (int p = 0; p < 15; ++p) {
            int r = cT2I[p], s = cT2J[p];
            float o[9];
            #pragma unroll
            for (int x = 0; x < 3; ++x)
                #pragma unroll
                for (int y = 0; y < 3; ++y) o[x*3+y] = m1[r*3+x] * m1[s*3+y];
            #pragma unroll
            for (int t = 0; t < 5; ++t) {
                float v = 0.f;
                #pragma unroll
                for (int x = 0; x < 3; ++x)
                    #pragma unroll
                    for (int y = 0; y < 3; ++y)
                        v += o[x*3+y] * m2[t*6 + s2c(x,y)];
                STF(85 + p*5 + t, v);
            }
        }
    } else {
        // c3, c7
        float m1[15], m2[30], m3[50];
        #pragma unroll
        for (int e = 0; e < 15; ++e) m1[e] = LDM(5 + e);
        #pragma unroll
        for (int e = 0; e < 30; ++e) m2[e] = LDM(20 + e);
        #pragma unroll
        for (int e = 0; e < 50; ++e) m3[e] = LDM(50 + e);
        #pragma unroll
        for (int p = 0; p < 15; ++p) {
            int r = cT2I[p], s = cT2J[p];
            float v = 0.f;
            #pragma unroll
            for (int k = 0; k < 10; ++k) v += cW3[k] * m3[r*10+k] * m3[s*10+k];
            STF(35 + p, v);
        }
        #pragma unroll
        for (int r = 0; r < 5; ++r)
            #pragma unroll
            for (int s = 0; s < 5; ++s) {
                float A3z[3];
                #pragma unroll
                for (int z = 0; z < 3; ++z) {
                    float v = 0.f;
                    #pragma unroll
                    for (int x = 0; x < 3; ++x)
                        #pragma unroll
                        for (int y = 0; y < 3; ++y)
                            v += m3[r*10 + s3c(x,y,z)] * m2[s*6 + s2c(x,y)];
                    A3z[z] = v;
                }
                #pragma unroll
                for (int t = 0; t < 5; ++t) {
                    float v = A3z[0]*m1[t*3] + A3z[1]*m1[t*3+1] + A3z[2]*m1[t*3+2];
                    STF(235 + r*25 + s*5 + t, v);
                }
            }
    }
    __syncthreads();

    // coalesced copy-out: wave wv handles rows wv*16 .. wv*16+15
    __hip_bfloat16* dst = feats + (size_t)blockIdx.x * 64 * KP1;
    #pragma unroll
    for (int rr = 0; rr < 16; ++rr) {
        int row = wv * 16 + rr;
        #pragma unroll
        for (int it = 0; it < 3; ++it) {
            uint32_t v = *(const uint32_t*)&ldsF[row][(it*64 + lane)*2];
            *(uint32_t*)&dst[(size_t)row * KP1 + (size_t)(it*64 + lane)*2] = v;
        }
    }
    #undef LDM
    #undef STF
}

// ---------- bf16 MFMA GEMM, 128x128 tile, BK=64, global_load_lds staging ----------
// Fewer barrier-drains: 32 MFMA + 16 ds_read per wave per barrier (vs 16+8 at BK=32).
// LDS row = 8 chunks of 16B; XOR swizzle within each 64B half applied to the
// GLOBAL source chunk (linear LDS dest): src = (c&4) | ((c&3)^swz(row)).
// Readers: slot = row*8 + s*4 + (quad^swz(row)), s = K-substep 0..1.
// 1D grid with XCD-grouped swizzle: mt = (bid>>5)*8 + (bid&7), nt = (bid>>3)&3.
__global__ __launch_bounds__(256) void gemm_mfma_swish(
    const __hip_bfloat16* __restrict__ A, const __hip_bfloat16* __restrict__ Bt,
    const float* __restrict__ bias, __hip_bfloat16* __restrict__ C,
    const float* __restrict__ w3, float* __restrict__ outacc,
    const int* __restrict__ Zmask,
    int Kp, int M, int Mtiles, float alpha, float a3, int fuse)
{
    __shared__ float4 As[2][1024];   // 128 rows x 8 chunks x 2 buffers = 32 KB
    __shared__ float4 Bs[2][1024];   // 32 KB
    int tid = threadIdx.x;
    int wave = tid >> 6, lane = tid & 63;
    int quad = lane >> 4, l16 = lane & 15;
    int wm = wave >> 1, wn = wave & 1;   // 2x2 waves: 64-row x 64-col each
    int bid = blockIdx.x;
    int mt = (bid >> 5) * 8 + (bid & 7);
    int nt = (bid >> 3) & 3;
    if (mt >= Mtiles) return;
    int rowBase = mt * 128;
    int colBase = nt * 128;

    floatx4 acc[4][4] = {};

    // staging: pass p (0..3) covers slots p*256 + tid; row = slot>>3, c = slot&7
    // global src chunk = (c&4) | ((c&3)^swz(row)); LDS dest is linear slot*16.
    int srow[4], schunk[4];
    #pragma unroll
    for (int p = 0; p < 4; ++p) {
        int slot = p * 256 + tid;
        int r = slot >> 3, c = slot & 7;
        srow[p] = r;
        schunk[p] = (c & 4) | ((c & 3) ^ ((r >> 1) & 3));
    }
    const char* gA[4]; const char* gB[4];
    #pragma unroll
    for (int p = 0; p < 4; ++p) {
        gA[p] = (const char*)A  + ((size_t)(rowBase + srow[p]) * Kp) * 2 + schunk[p] * 16;
        gB[p] = (const char*)Bt + ((size_t)(colBase + srow[p]) * Kp) * 2 + schunk[p] * 16;
    }
    char* lA = (char*)As;
    char* lB = (char*)Bs;
    int wvoff = wave << 10;          // wave-uniform LDS base offset within a pass

    // fragment read base slots (add s*4 for K-substep s)
    int posA[4], posB[4];
    #pragma unroll
    for (int t = 0; t < 4; ++t) {
        int rr = wm * 64 + t * 16 + l16;
        posA[t] = rr * 8 + (quad ^ ((rr >> 1) & 3));
    }
    #pragma unroll
    for (int u = 0; u < 4; ++u) {
        int cc = wn * 64 + u * 16 + l16;
        posB[u] = cc * 8 + (quad ^ ((cc >> 1) & 3));
    }

    int nK = Kp >> 6;   // BK = 64 bf16 = 128 B per row per iter

    // prologue: stage K-tile 0 into buffer 0
    #pragma unroll
    for (int p = 0; p < 4; ++p) {
        int lo = (p << 12) + wvoff;
        gload_lds16(gA[p], lA + lo);
        gload_lds16(gB[p], lB + lo);
    }
    __syncthreads();

    for (int kt = 0; kt < nK; ++kt) {
        int buf = kt & 1;
        if (kt + 1 < nK) {
            int go = (kt + 1) << 7;                 // 64 bf16 = 128 bytes
            int lbase = ((buf ^ 1) << 14) + wvoff;  // other buffer (16 KB stride)
            #pragma unroll
            for (int p = 0; p < 4; ++p) {
                int lo = lbase + (p << 12);
                gload_lds16(gA[p] + go, lA + lo);
                gload_lds16(gB[p] + go, lB + lo);
            }
        }
        #pragma unroll
        for (int s = 0; s < 2; ++s) {
            short8 af[4], bf[4];
            #pragma unroll
            for (int t = 0; t < 4; ++t) af[t] = *(const short8*)(As[buf] + posA[t] + s * 4);
            #pragma unroll
            for (int u = 0; u < 4; ++u) bf[u] = *(const short8*)(Bs[buf] + posB[u] + s * 4);
            #pragma unroll
            for (int t = 0; t < 4; ++t)
                #pragma unroll
                for (int u = 0; u < 4; ++u)
                    acc[t][u] = __builtin_amdgcn_mfma_f32_16x16x32_bf16(
                        af[t], bf[u], acc[t][u], 0, 0, 0);
        }
        // barrier: (a) all lanes done reading buf, (b) drains vmcnt so the
        // staged buf^1 is complete before next iteration reads it.
        __syncthreads();
    }

    if (!fuse) {
        #pragma unroll
        for (int u = 0; u < 4; ++u) {
            int col = colBase + wn * 64 + u * 16 + l16;
            float bc = 0.1f * bias[col];
            #pragma unroll
            for (int t = 0; t < 4; ++t) {
                int row0 = rowBase + wm * 64 + t * 16 + quad * 4;
                #pragma unroll
                for (int r = 0; r < 4; ++r) {
                    float x = alpha * acc[t][u][r] + bc;
                    float v = x / (1.f + expf(-x));
                    C[(size_t)(row0 + r) * UNITS + col] = __float2bfloat16(v);
                }
            }
        }
    } else {
        float rowsum[4][4] = {};
        #pragma unroll
        for (int u = 0; u < 4; ++u) {
            int col = colBase + wn * 64 + u * 16 + l16;
            float bc = 0.1f * bias[col];
            float w3c = w3[col] * a3;
            #pragma unroll
            for (int t = 0; t < 4; ++t)
                #pragma unroll
                for (int r = 0; r < 4; ++r) {
                    float x = alpha * acc[t][u][r] + bc;
                    float v = x / (1.f + expf(-x));
                    rowsum[t][r] += v * w3c;
                }
        }
        #pragma unroll
        for (int t = 0; t < 4; ++t)
            #pragma unroll
            for (int r = 0; r < 4; ++r) {
                float s = rowsum[t][r];
                s += __shfl_xor(s, 1, 64);
                s += __shfl_xor(s, 2, 64);
                s += __shfl_xor(s, 4, 64);
                s += __shfl_xor(s, 8, 64);
                rowsum[t][r] = s;
            }
        if (l16 == 0) {
            #pragma unroll
            for (int t = 0; t < 4; ++t) {
                int row0 = rowBase + wm * 64 + t * 16 + quad * 4;
                #pragma unroll
                for (int r = 0; r < 4; ++r) {
                    int row = row0 + r;
                    if (row < M && Zmask[row] > 0)
                        atomicAdd(&outacc[row], rowsum[t][r]);
                }
            }
        }
    }
}

static inline size_t align_up(size_t x, size_t a) { return (x + a - 1) & ~(a - 1); }

extern "C" void kernel_launch(void* const* d_in, const int* in_sizes, int n_in,
                              void* d_out, int out_size, void* d_ws, size_t ws_size,
                              hipStream_t stream)
{
    const float* R       = (const float*)d_in[0];
    const int*   Z       = (const int*)  d_in[1];
    const int*   nbr     = (const int*)  d_in[2];
    const float* offsets = (const float*)d_in[4];
    const float* emb     = (const float*)d_in[5];
    const float* W1      = (const float*)d_in[6];
    const float* b1      = (const float*)d_in[7];
    const float* W2      = (const float*)d_in[8];
    const float* b2      = (const float*)d_in[9];
    const float* W3      = (const float*)d_in[10];
    const float* b3      = (const float*)d_in[11];

    int natoms = in_sizes[0] / 3;
    int npairs = in_sizes[2] / 2;
    int Mpad = ((natoms + 127) / 128) * 128;
    int Mtiles = Mpad / 128;

    char* ws = (char*)d_ws;
    size_t off = 0;
    int* counts = (int*)(ws + off); off = align_up(off + natoms*4, 256);
    float* tmpRec = (float*)(ws + off); off = align_up(off + (size_t)natoms*CAP*8*4, 256);
    float* momG = (float*)(ws + off); off = align_up(off + (size_t)Mpad*100*4, 256);
    __hip_bfloat16* W1t   = (__hip_bfloat16*)(ws + off); off = align_up(off + (size_t)UNITS*KP1*2, 256);
    __hip_bfloat16* W2t   = (__hip_bfloat16*)(ws + off); off = align_up(off + (size_t)UNITS*UNITS*2, 256);
    __hip_bfloat16* feats = (__hip_bfloat16*)(ws + off); off = align_up(off + (size_t)Mpad*KP1*2, 256);
    __hip_bfloat16* h1    = (__hip_bfloat16*)(ws + off); off = align_up(off + (size_t)Mpad*UNITS*2, 256);

    // host-side double-precision basis constants (exact vs numpy reference)
    BasisConsts bc;
    {
        const double betta = 49.0 / 36.0;
        const double delta = 5.5 / 6.0;
        const double log2e = 1.4426950408889634073599246810;
        bc.f0k = (float)(-betta * log2e);
        bc.kg  = (float)(2.0 * betta * delta * log2e);
        for (int b = 0; b < 6; ++b)
            bc.c[b] = (float)exp(-betta * delta * (1.0 + delta * (2*b + 1)));
        bc.scale = (float)(pow(2.0 * betta / M_PI, 0.75) / sqrt(7.0));
    }

    hipMemsetAsync(counts, 0, (size_t)natoms * sizeof(int), stream);

    int pgrid = (npairs + 255) / 256;
    int totalBlocks = pgrid + 448 + (natoms + 255) / 256;
    pair_prep_kernel<<<dim3(totalBlocks), 256, 0, stream>>>(
        R, Z, nbr, offsets, emb, counts, tmpRec, npairs, bc,
        W1, W2, W1t, W2t, (float*)d_out, b3, pgrid, natoms);

    moment_kernel<<<dim3(Mpad / 4), 256, 0, stream>>>(
        tmpRec, counts, momG, natoms);
    feat_kernel<<<dim3(Mpad / 64), 256, 0, stream>>>(momG, feats);

    float a1 = 1.0f / sqrtf((float)NFEAT);
    float a2 = 1.0f / sqrtf((float)UNITS);
    int gemmGrid = ((Mtiles + 7) / 8) * 8 * 4;
    gemm_mfma_swish<<<dim3(gemmGrid), 256, 0, stream>>>(
        feats, W1t, b1, h1, nullptr, nullptr, nullptr, KP1, natoms, Mtiles, a1, 0.f, 0);
    gemm_mfma_swish<<<dim3(gemmGrid), 256, 0, stream>>>(
        h1, W2t, b2, nullptr, W3, (float*)d_out, Z, UNITS, natoms, Mtiles, a2, a2, 1);
}